// Round 13
// baseline (468.183 us; speedup 1.0000x reference)
//
#include <hip/hip_runtime.h>
#include <hip/hip_bf16.h>
#include <math.h>

#define S_LEN 2048
#define D_DIM 2048
#define H_NUM 32
#define HD_DIM 64
#define FF_DIM 8192
#define QMAX 255.0f
#define LOG2E 1.4426950408889634f

typedef __attribute__((ext_vector_type(4))) float f32x4;
typedef __attribute__((ext_vector_type(4))) int i32x4;
typedef __attribute__((ext_vector_type(8))) __bf16 bf16x8;
typedef unsigned short u16;
typedef signed char i8;

__device__ __forceinline__ u16 f32i_to_bf16(float v) {
  return (u16)(__float_as_uint(v) >> 16);  // exact for ints in [-255,255]
}
__device__ __forceinline__ u16 f32_to_bf16_rne(float v) {
  __bf16 b = (__bf16)v;
  return *(u16*)&b;
}
__device__ __forceinline__ float bf16_to_f32(u16 u) {
  return __uint_as_float((unsigned int)u << 16);
}
__device__ __forceinline__ int pack4_i8(float q0, float q1, float q2, float q3) {
  int c0 = (int)q0 - 128, c1 = (int)q1 - 128, c2 = (int)q2 - 128, c3 = (int)q3 - 128;
  return (c0 & 0xFF) | ((c1 & 0xFF) << 8) | ((c2 & 0xFF) << 16) | ((c3 & 0xFF) << 24);
}

__device__ __forceinline__ float wred_sum(float v) {
#pragma unroll
  for (int o = 1; o < 64; o <<= 1) v += __shfl_xor(v, o, 64);
  return v;
}
__device__ __forceinline__ float wred_min(float v) {
#pragma unroll
  for (int o = 1; o < 64; o <<= 1) v = fminf(v, __shfl_xor(v, o, 64));
  return v;
}
__device__ __forceinline__ float wred_max(float v) {
#pragma unroll
  for (int o = 1; o < 64; o <<= 1) v = fmaxf(v, __shfl_xor(v, o, 64));
  return v;
}

__device__ __forceinline__ void gload_lds16(const void* g, void* l) {
  __builtin_amdgcn_global_load_lds(
      (__attribute__((address_space(1))) void*)(g),
      (__attribute__((address_space(3))) void*)(l), 16, 0, 0);
}

// bijective XCD-aware swizzle, COLUMN-major decode: each XCD chunk covers a few
// full B-panels (bx) across all A-rows (by) -> per-XCD L2 set = panels + A.
__device__ __forceinline__ void xcd_swz(int& bx, int& by) {
  const int gy = gridDim.y;
  const int nwg = gridDim.x * gy;
  const int orig = blockIdx.y + gy * blockIdx.x;   // column-major index
  const int swz = (orig & 7) * (nwg >> 3) + (orig >> 3);
  by = swz % gy;
  bx = swz / gy;
}

// ---- LayerNorm + per-token quant -> i8 (q-128) + scale + z'(=128-zp) + half-sums ----
__global__ __launch_bounds__(256) void ln_quant_i8(const float* __restrict__ x,
                                                   const float* __restrict__ g,
                                                   const float* __restrict__ bvec,
                                                   i8* __restrict__ out,
                                                   float* __restrict__ srow,
                                                   float* __restrict__ zrow,
                                                   float* __restrict__ S0row,
                                                   float* __restrict__ S1row) {
  __shared__ float red[8];
  const int row = blockIdx.x, tid = threadIdx.x;
  const float4* xr = (const float4*)(x + (size_t)row * D_DIM);
  const float4* g4 = (const float4*)g;
  const float4* b4 = (const float4*)bvec;

  float4 v0 = xr[tid], v1 = xr[tid + 256];
  float s = v0.x + v0.y + v0.z + v0.w + v1.x + v1.y + v1.z + v1.w;
  float ss = v0.x * v0.x + v0.y * v0.y + v0.z * v0.z + v0.w * v0.w +
             v1.x * v1.x + v1.y * v1.y + v1.z * v1.z + v1.w * v1.w;
  s = wred_sum(s); ss = wred_sum(ss);
  if ((tid & 63) == 0) { red[tid >> 6] = s; red[4 + (tid >> 6)] = ss; }
  __syncthreads();
  float mu = (red[0] + red[1] + red[2] + red[3]) / (float)D_DIM;
  float var = (red[4] + red[5] + red[6] + red[7]) / (float)D_DIM - mu * mu;
  float rstd = 1.0f / sqrtf(var + 1e-5f);
  __syncthreads();

  float mn = 0.f, mx = 0.f;
  float4 n0, n1;
  {
    float4 gg = g4[tid], bb = b4[tid];
    n0.x = (v0.x - mu) * rstd * gg.x + bb.x; n0.y = (v0.y - mu) * rstd * gg.y + bb.y;
    n0.z = (v0.z - mu) * rstd * gg.z + bb.z; n0.w = (v0.w - mu) * rstd * gg.w + bb.w;
    gg = g4[tid + 256]; bb = b4[tid + 256];
    n1.x = (v1.x - mu) * rstd * gg.x + bb.x; n1.y = (v1.y - mu) * rstd * gg.y + bb.y;
    n1.z = (v1.z - mu) * rstd * gg.z + bb.z; n1.w = (v1.w - mu) * rstd * gg.w + bb.w;
    mn = fminf(mn, fminf(fminf(n0.x, n0.y), fminf(n0.z, n0.w)));
    mn = fminf(mn, fminf(fminf(n1.x, n1.y), fminf(n1.z, n1.w)));
    mx = fmaxf(mx, fmaxf(fmaxf(n0.x, n0.y), fmaxf(n0.z, n0.w)));
    mx = fmaxf(mx, fmaxf(fmaxf(n1.x, n1.y), fmaxf(n1.z, n1.w)));
  }
  mn = wred_min(mn); mx = wred_max(mx);
  if ((tid & 63) == 0) { red[tid >> 6] = mn; red[4 + (tid >> 6)] = mx; }
  __syncthreads();
  mn = fminf(fminf(red[0], red[1]), fminf(red[2], red[3]));
  mx = fmaxf(fmaxf(red[4], red[5]), fmaxf(red[6], red[7]));
  float scale = fmaxf((mx - mn) / QMAX, 1e-5f);
  float zp = rintf(-mn / scale);
  if (tid == 0) { srow[row] = scale; zrow[row] = 128.0f - zp; }

  float q00 = fminf(fmaxf(rintf(n0.x / scale) + zp, 0.f), QMAX);
  float q01 = fminf(fmaxf(rintf(n0.y / scale) + zp, 0.f), QMAX);
  float q02 = fminf(fmaxf(rintf(n0.z / scale) + zp, 0.f), QMAX);
  float q03 = fminf(fmaxf(rintf(n0.w / scale) + zp, 0.f), QMAX);
  float q10 = fminf(fmaxf(rintf(n1.x / scale) + zp, 0.f), QMAX);
  float q11 = fminf(fmaxf(rintf(n1.y / scale) + zp, 0.f), QMAX);
  float q12 = fminf(fmaxf(rintf(n1.z / scale) + zp, 0.f), QMAX);
  float q13 = fminf(fmaxf(rintf(n1.w / scale) + zp, 0.f), QMAX);
  *(int*)&out[(size_t)row * D_DIM + tid * 4] = pack4_i8(q00, q01, q02, q03);
  *(int*)&out[(size_t)row * D_DIM + 1024 + tid * 4] = pack4_i8(q10, q11, q12, q13);
  float s0 = q00 + q01 + q02 + q03 - 512.f;
  float s1 = q10 + q11 + q12 + q13 - 512.f;
  __syncthreads();
  s0 = wred_sum(s0); s1 = wred_sum(s1);
  if ((tid & 63) == 0) { red[tid >> 6] = s0; red[4 + (tid >> 6)] = s1; }
  __syncthreads();
  if (tid == 0) {
    S0row[row] = red[0] + red[1] + red[2] + red[3];
    S1row[row] = red[4] + red[5] + red[6] + red[7];
  }
}

// ---- fp32 ctx row -> quant -> i8 + params ----
__global__ __launch_bounds__(256) void act_quant_i8(const float* __restrict__ x,
                                                    i8* __restrict__ out,
                                                    float* __restrict__ srow,
                                                    float* __restrict__ zrow,
                                                    float* __restrict__ S0row,
                                                    float* __restrict__ S1row) {
  __shared__ float red[8];
  const int row = blockIdx.x, tid = threadIdx.x;
  const float4* xr = (const float4*)(x + (size_t)row * D_DIM);
  float4 n0 = xr[tid], n1 = xr[tid + 256];
  float mn = 0.f, mx = 0.f;
  mn = fminf(mn, fminf(fminf(n0.x, n0.y), fminf(n0.z, n0.w)));
  mn = fminf(mn, fminf(fminf(n1.x, n1.y), fminf(n1.z, n1.w)));
  mx = fmaxf(mx, fmaxf(fmaxf(n0.x, n0.y), fmaxf(n0.z, n0.w)));
  mx = fmaxf(mx, fmaxf(fmaxf(n1.x, n1.y), fmaxf(n1.z, n1.w)));
  mn = wred_min(mn); mx = wred_max(mx);
  if ((tid & 63) == 0) { red[tid >> 6] = mn; red[4 + (tid >> 6)] = mx; }
  __syncthreads();
  mn = fminf(fminf(red[0], red[1]), fminf(red[2], red[3]));
  mx = fmaxf(fmaxf(red[4], red[5]), fmaxf(red[6], red[7]));
  float scale = fmaxf((mx - mn) / QMAX, 1e-5f);
  float zp = rintf(-mn / scale);
  if (tid == 0) { srow[row] = scale; zrow[row] = 128.0f - zp; }
  float q00 = fminf(fmaxf(rintf(n0.x / scale) + zp, 0.f), QMAX);
  float q01 = fminf(fmaxf(rintf(n0.y / scale) + zp, 0.f), QMAX);
  float q02 = fminf(fmaxf(rintf(n0.z / scale) + zp, 0.f), QMAX);
  float q03 = fminf(fmaxf(rintf(n0.w / scale) + zp, 0.f), QMAX);
  float q10 = fminf(fmaxf(rintf(n1.x / scale) + zp, 0.f), QMAX);
  float q11 = fminf(fmaxf(rintf(n1.y / scale) + zp, 0.f), QMAX);
  float q12 = fminf(fmaxf(rintf(n1.z / scale) + zp, 0.f), QMAX);
  float q13 = fminf(fmaxf(rintf(n1.w / scale) + zp, 0.f), QMAX);
  *(int*)&out[(size_t)row * D_DIM + tid * 4] = pack4_i8(q00, q01, q02, q03);
  *(int*)&out[(size_t)row * D_DIM + 1024 + tid * 4] = pack4_i8(q10, q11, q12, q13);
  float s0 = q00 + q01 + q02 + q03 - 512.f;
  float s1 = q10 + q11 + q12 + q13 - 512.f;
  __syncthreads();
  s0 = wred_sum(s0); s1 = wred_sum(s1);
  if ((tid & 63) == 0) { red[tid >> 6] = s0; red[4 + (tid >> 6)] = s1; }
  __syncthreads();
  if (tid == 0) {
    S0row[row] = red[0] + red[1] + red[2] + red[3];
    S1row[row] = red[4] + red[5] + red[6] + red[7];
  }
}

// ---- single-pass K=2048 weight quant body (row fully register-cached) ----
__device__ __forceinline__ void wquantD_body(const float* __restrict__ wr0,
                                             i8* __restrict__ wo,
                                             float* __restrict__ sc,
                                             float* __restrict__ zc,
                                             float* __restrict__ S0c,
                                             float* __restrict__ S1c, int row) {
  __shared__ float red[8];
  const int tid = threadIdx.x;
  const float4* wr = (const float4*)wr0;
  float4 v0 = wr[tid], v1 = wr[tid + 256];
  float mn = 0.f, mx = 0.f;
  mn = fminf(mn, fminf(fminf(v0.x, v0.y), fminf(v0.z, v0.w)));
  mn = fminf(mn, fminf(fminf(v1.x, v1.y), fminf(v1.z, v1.w)));
  mx = fmaxf(mx, fmaxf(fmaxf(v0.x, v0.y), fmaxf(v0.z, v0.w)));
  mx = fmaxf(mx, fmaxf(fmaxf(v1.x, v1.y), fmaxf(v1.z, v1.w)));
  mn = wred_min(mn); mx = wred_max(mx);
  if ((tid & 63) == 0) { red[tid >> 6] = mn; red[4 + (tid >> 6)] = mx; }
  __syncthreads();
  mn = fminf(fminf(red[0], red[1]), fminf(red[2], red[3]));
  mx = fmaxf(fmaxf(red[4], red[5]), fmaxf(red[6], red[7]));
  float scale = fmaxf((mx - mn) / QMAX, 1e-5f);
  float zp = rintf(-mn / scale);
  if (tid == 0) { sc[row] = scale; zc[row] = 128.0f - zp; }
  float q00 = fminf(fmaxf(rintf(v0.x / scale) + zp, 0.f), QMAX);
  float q01 = fminf(fmaxf(rintf(v0.y / scale) + zp, 0.f), QMAX);
  float q02 = fminf(fmaxf(rintf(v0.z / scale) + zp, 0.f), QMAX);
  float q03 = fminf(fmaxf(rintf(v0.w / scale) + zp, 0.f), QMAX);
  float q10 = fminf(fmaxf(rintf(v1.x / scale) + zp, 0.f), QMAX);
  float q11 = fminf(fmaxf(rintf(v1.y / scale) + zp, 0.f), QMAX);
  float q12 = fminf(fmaxf(rintf(v1.z / scale) + zp, 0.f), QMAX);
  float q13 = fminf(fmaxf(rintf(v1.w / scale) + zp, 0.f), QMAX);
  *(int*)&wo[tid * 4] = pack4_i8(q00, q01, q02, q03);
  *(int*)&wo[1024 + tid * 4] = pack4_i8(q10, q11, q12, q13);
  float s0 = q00 + q01 + q02 + q03 - 512.f;   // elems < 1024 (first K-half)
  float s1 = q10 + q11 + q12 + q13 - 512.f;
  __syncthreads();
  s0 = wred_sum(s0); s1 = wred_sum(s1);
  if ((tid & 63) == 0) { red[tid >> 6] = s0; red[4 + (tid >> 6)] = s1; }
  __syncthreads();
  if (tid == 0) {
    S0c[row] = red[0] + red[1] + red[2] + red[3];
    S1c[row] = red[4] + red[5] + red[6] + red[7];
  }
}

// five K=2048 weights (Wq,Wk,Wv,Wo: 2048 rows each; W1: 8192 rows) in one launch
__global__ __launch_bounds__(256) void wquantD_i8(
    const float* __restrict__ Wq, i8* __restrict__ Oq, float* sq_, float* zq_, float* aq_, float* bq_,
    const float* __restrict__ Wk, i8* __restrict__ Ok, float* sk_, float* zk_, float* ak_, float* bk_,
    const float* __restrict__ Wv, i8* __restrict__ Ov, float* sv_, float* zv_, float* av_, float* bv_,
    const float* __restrict__ Wo, i8* __restrict__ Oo, float* so_, float* zo_, float* ao_, float* bo_,
    const float* __restrict__ W1, i8* __restrict__ O1, float* s1_, float* z1_, float* a1_, float* b1_) {
  const int b = blockIdx.x;
  int which, row;
  if (b < 4 * D_DIM) { which = b >> 11; row = b & (D_DIM - 1); }
  else { which = 4; row = b - 4 * D_DIM; }
  const float* W = (which == 0) ? Wq : (which == 1) ? Wk : (which == 2) ? Wv : (which == 3) ? Wo : W1;
  i8* O = (which == 0) ? Oq : (which == 1) ? Ok : (which == 2) ? Ov : (which == 3) ? Oo : O1;
  float* sc = (which == 0) ? sq_ : (which == 1) ? sk_ : (which == 2) ? sv_ : (which == 3) ? so_ : s1_;
  float* zc = (which == 0) ? zq_ : (which == 1) ? zk_ : (which == 2) ? zv_ : (which == 3) ? zo_ : z1_;
  float* Sa = (which == 0) ? aq_ : (which == 1) ? ak_ : (which == 2) ? av_ : (which == 3) ? ao_ : a1_;
  float* Sb = (which == 0) ? bq_ : (which == 1) ? bk_ : (which == 2) ? bv_ : (which == 3) ? bo_ : b1_;
  wquantD_body(W + (size_t)row * D_DIM, O + (size_t)row * D_DIM, sc, zc, Sa, Sb, row);
}

// ---- single-pass K=8192 weight quant (W2): 8 x float4 register-cached ----
__global__ __launch_bounds__(256) void wquantW2_i8(const float* __restrict__ W,
                                                   i8* __restrict__ Wi,
                                                   float* __restrict__ sc,
                                                   float* __restrict__ zc,
                                                   float* __restrict__ S0c,
                                                   float* __restrict__ S1c) {
  __shared__ float red[8];
  const int row = blockIdx.x, tid = threadIdx.x;
  const float4* wr = (const float4*)(W + (size_t)row * FF_DIM);
  float4 v[8];
#pragma unroll
  for (int j = 0; j < 8; ++j) v[j] = wr[tid + 256 * j];
  float mn = 0.f, mx = 0.f;
#pragma unroll
  for (int j = 0; j < 8; ++j) {
    mn = fminf(mn, fminf(fminf(v[j].x, v[j].y), fminf(v[j].z, v[j].w)));
    mx = fmaxf(mx, fmaxf(fmaxf(v[j].x, v[j].y), fmaxf(v[j].z, v[j].w)));
  }
  mn = wred_min(mn); mx = wred_max(mx);
  if ((tid & 63) == 0) { red[tid >> 6] = mn; red[4 + (tid >> 6)] = mx; }
  __syncthreads();
  mn = fminf(fminf(red[0], red[1]), fminf(red[2], red[3]));
  mx = fmaxf(fmaxf(red[4], red[5]), fmaxf(red[6], red[7]));
  float scale = fmaxf((mx - mn) / QMAX, 1e-5f);
  float zp = rintf(-mn / scale);
  if (tid == 0) { sc[row] = scale; zc[row] = 128.0f - zp; }
  float s0 = 0.f, s1 = 0.f;
#pragma unroll
  for (int j = 0; j < 8; ++j) {
    float q0 = fminf(fmaxf(rintf(v[j].x / scale) + zp, 0.f), QMAX);
    float q1 = fminf(fmaxf(rintf(v[j].y / scale) + zp, 0.f), QMAX);
    float q2 = fminf(fmaxf(rintf(v[j].z / scale) + zp, 0.f), QMAX);
    float q3 = fminf(fmaxf(rintf(v[j].w / scale) + zp, 0.f), QMAX);
    *(int*)&Wi[(size_t)row * FF_DIM + (tid + 256 * j) * 4] = pack4_i8(q0, q1, q2, q3);
    float gs = q0 + q1 + q2 + q3 - 512.f;
    if (j < 4) s0 += gs; else s1 += gs;   // halves at K/2 = 4096
  }
  __syncthreads();
  s0 = wred_sum(s0); s1 = wred_sum(s1);
  if ((tid & 63) == 0) { red[tid >> 6] = s0; red[4 + (tid >> 6)] = s1; }
  __syncthreads();
  if (tid == 0) {
    S0c[row] = red[0] + red[1] + red[2] + red[3];
    S1c[row] = red[4] + red[5] + red[6] + red[7];
  }
}

// ---- requant q/k/v in one launch ----
__global__ __launch_bounds__(256) void requant3(
    const u16* __restrict__ qv, const float* __restrict__ tqmn, const float* __restrict__ tqmx,
    u16* __restrict__ qo, float* __restrict__ sqv,
    const u16* __restrict__ kv, const float* __restrict__ tkmn, const float* __restrict__ tkmx,
    u16* __restrict__ ko, float* __restrict__ skv,
    const u16* __restrict__ vv, const float* __restrict__ tvmn, const float* __restrict__ tvmx,
    u16* __restrict__ vo) {
  __shared__ float red[8];
  const int wh = blockIdx.x >> 11;
  const int row = blockIdx.x & (S_LEN - 1);
  const int tid = threadIdx.x;
  const u16* vals = (wh == 0) ? qv : (wh == 1) ? kv : vv;
  const float* tmn = (wh == 0) ? tqmn : (wh == 1) ? tkmn : tvmn;
  const float* tmx = (wh == 0) ? tqmx : (wh == 1) ? tkmx : tvmx;
  u16* out = (wh == 0) ? qo : (wh == 1) ? ko : vo;
  float* srow = (wh == 0) ? sqv : (wh == 1) ? skv : nullptr;
  const int value_mode = (wh == 2) ? 1 : 0;

  float mn = 0.f, mx = 0.f;
  if (tid < 32) {
    mn = tmn[(size_t)row * 32 + tid];
    mx = tmx[(size_t)row * 32 + tid];
  }
  mn = wred_min(mn); mx = wred_max(mx);
  if ((tid & 63) == 0) { red[tid >> 6] = mn; red[4 + (tid >> 6)] = mx; }
  __syncthreads();
  mn = fminf(fminf(red[0], red[1]), fminf(red[2], red[3]));
  mx = fmaxf(fmaxf(red[4], red[5]), fmaxf(red[6], red[7]));
  mn = fminf(mn, 0.f); mx = fmaxf(mx, 0.f);
  float scale = fmaxf((mx - mn) / QMAX, 1e-5f);
  float zp = rintf(-mn / scale);
  if (srow && tid == 0) srow[row] = scale;
  const ushort4* vr = (const ushort4*)(vals + (size_t)row * D_DIM);
  ushort4* orow = (ushort4*)(out + (size_t)row * D_DIM);
  for (int i = tid; i < D_DIM / 4; i += 256) {
    ushort4 u = vr[i];
    float q0 = fminf(fmaxf(rintf(bf16_to_f32(u.x) / scale) + zp, 0.f), QMAX) - zp;
    float q1 = fminf(fmaxf(rintf(bf16_to_f32(u.y) / scale) + zp, 0.f), QMAX) - zp;
    float q2 = fminf(fmaxf(rintf(bf16_to_f32(u.z) / scale) + zp, 0.f), QMAX) - zp;
    float q3 = fminf(fmaxf(rintf(bf16_to_f32(u.w) / scale) + zp, 0.f), QMAX) - zp;
    ushort4 o;
    if (value_mode) {
      o.x = f32_to_bf16_rne(q0 * scale); o.y = f32_to_bf16_rne(q1 * scale);
      o.z = f32_to_bf16_rne(q2 * scale); o.w = f32_to_bf16_rne(q3 * scale);
    } else {
      o.x = f32i_to_bf16(q0); o.y = f32i_to_bf16(q1);
      o.z = f32i_to_bf16(q2); o.w = f32i_to_bf16(q3);
    }
    orow[i] = o;
  }
}

// ---- transpose fake-quant V: vfb[S][D] -> vtb [H][64][S] (per-head V^T) ----
__global__ __launch_bounds__(256) void transpose_v(const u16* __restrict__ vfb,
                                                   u16* __restrict__ vtb) {
  __shared__ u16 Ts[64][66];
  const int j0 = blockIdx.x * 64;
  const int h = blockIdx.y;
  const int tid = threadIdx.x;
  for (int c = tid; c < 512; c += 256) {
    int r = c >> 3, ch = c & 7;
    *(float4*)&Ts[r][ch * 8] =
        *(const float4*)&vfb[(size_t)(j0 + r) * D_DIM + h * HD_DIM + ch * 8];
  }
  __syncthreads();
  for (int c = tid; c < 512; c += 256) {
    int d = c >> 3, ch = c & 7;
    u16 tmp[8];
#pragma unroll
    for (int e = 0; e < 8; ++e) tmp[e] = Ts[ch * 8 + e][d];
    *(float4*)&vtb[(size_t)(h * HD_DIM + d) * S_LEN + j0 + ch * 8] = *(float4*)tmp;
  }
}

// ---- requant f1 (relu, zp=0) ----
__global__ __launch_bounds__(256) void requant_ff_i8(const u16* __restrict__ vals,
                                                     const float* __restrict__ tmx,
                                                     i8* __restrict__ out,
                                                     float* __restrict__ srow,
                                                     float* __restrict__ zrow,
                                                     float* __restrict__ S0row,
                                                     float* __restrict__ S1row) {
  __shared__ float red[8];
  const int row = blockIdx.x, tid = threadIdx.x;
  float mx = (tid < 128) ? tmx[(size_t)row * 128 + tid] : 0.f;
  mx = wred_max(mx);
  if ((tid & 63) == 0) red[tid >> 6] = mx;
  __syncthreads();
  mx = fmaxf(fmaxf(red[0], red[1]), fmaxf(red[2], red[3]));
  mx = fmaxf(mx, 0.f);
  float scale = fmaxf(mx / QMAX, 1e-5f);
  if (tid == 0) { srow[row] = scale; zrow[row] = 128.0f; }
  const ushort4* vr = (const ushort4*)(vals + (size_t)row * FF_DIM);
  const int N4 = FF_DIM >> 2;
  float s0 = 0.f, s1 = 0.f;
  for (int i = tid; i < N4; i += 256) {
    ushort4 u = vr[i];
    float q0 = fminf(fmaxf(rintf(bf16_to_f32(u.x) / scale), 0.f), QMAX);
    float q1 = fminf(fmaxf(rintf(bf16_to_f32(u.y) / scale), 0.f), QMAX);
    float q2 = fminf(fmaxf(rintf(bf16_to_f32(u.z) / scale), 0.f), QMAX);
    float q3 = fminf(fmaxf(rintf(bf16_to_f32(u.w) / scale), 0.f), QMAX);
    *(int*)&out[(size_t)row * FF_DIM + i * 4] = pack4_i8(q0, q1, q2, q3);
    float gs = q0 + q1 + q2 + q3 - 512.f;
    if (i < 1024) s0 += gs; else s1 += gs;
  }
  __syncthreads();
  s0 = wred_sum(s0); s1 = wred_sum(s1);
  if ((tid & 63) == 0) { red[tid >> 6] = s0; red[4 + (tid >> 6)] = s1; }
  __syncthreads();
  if (tid == 0) {
    S0row[row] = red[0] + red[1] + red[2] + red[3];
    S1row[row] = red[4] + red[5] + red[6] + red[7];
  }
}

// ---- i8 double-buffered 128x128x64 MFMA body ----
__device__ __forceinline__ void gemm128_i8_db(
    const i8* __restrict__ A, const i8* __restrict__ B,
    int K, int bm, int bn, int k_begin, int k_end,
    i8* As, i8* Bs, i32x4 (&acc)[4][4]) {
  const int tid = threadIdx.x;
  const int wid = tid >> 6, lane = tid & 63;
  const int wr = wid >> 1, wc = wid & 1;
  const int lr = lane & 15, lk = lane >> 4;
  const int r0 = tid >> 2, c0 = (tid & 3) * 16;
  const int r1 = 64 + r0;
  const size_t ldsb0 = (size_t)(wid * 64) * 16;
  const size_t ldsb1 = (size_t)(256 + wid * 64) * 16;

  const i8* Ag0 = A + (size_t)(bm + r0) * K + c0;
  const i8* Ag1 = A + (size_t)(bm + r1) * K + c0;
  const i8* Bg0 = B + (size_t)(bn + r0) * K + c0;
  const i8* Bg1 = B + (size_t)(bn + r1) * K + c0;

  const int nt = (k_end - k_begin) >> 6;

#define STAGE_I8(t)                                   \
  {                                                   \
    const int _k = k_begin + (t) * 64;                \
    i8* _Ab = As + (size_t)((t) & 1) * 8192;          \
    i8* _Bb = Bs + (size_t)((t) & 1) * 8192;          \
    gload_lds16(Ag0 + _k, _Ab + ldsb0);               \
    gload_lds16(Ag1 + _k, _Ab + ldsb1);               \
    gload_lds16(Bg0 + _k, _Bb + ldsb0);               \
    gload_lds16(Bg1 + _k, _Bb + ldsb1);               \
  }

  STAGE_I8(0);
  __syncthreads();

  for (int t = 0; t < nt; ++t) {
    const i8* Ac = As + (size_t)(t & 1) * 8192;
    const i8* Bc = Bs + (size_t)(t & 1) * 8192;
    i32x4 af[4], bf[4];
#pragma unroll
    for (int mi = 0; mi < 4; ++mi)
      af[mi] = *(const i32x4*)&Ac[(size_t)(wr * 64 + mi * 16 + lr) * 64 + lk * 16];
#pragma unroll
    for (int ni = 0; ni < 4; ++ni)
      bf[ni] = *(const i32x4*)&Bc[(size_t)(wc * 64 + ni * 16 + lr) * 64 + lk * 16];
    if (t + 1 < nt) STAGE_I8(t + 1);
#pragma unroll
    for (int mi = 0; mi < 4; ++mi)
#pragma unroll
      for (int ni = 0; ni < 4; ++ni)
        acc[mi][ni] = __builtin_amdgcn_mfma_i32_16x16x64_i8(af[mi], bf[ni], acc[mi][ni], 0, 0, 0);
    __syncthreads();
  }
#undef STAGE_I8
}

// ---- fused QKV (i8) ----
__global__ __launch_bounds__(256) void gemm_qkv_i8(
    const i8* __restrict__ A, const float* __restrict__ sx, const float* __restrict__ zx,
    const float* __restrict__ Sx0, const float* __restrict__ Sx1,
    const i8* __restrict__ Bq, const float* __restrict__ sbq, const float* __restrict__ zbq,
    const float* __restrict__ Sq0, const float* __restrict__ Sq1,
    const float* __restrict__ biasq, u16* __restrict__ Cq,
    float* __restrict__ tqmn, float* __restrict__ tqmx,
    const i8* __restrict__ Bk, const float* __restrict__ sbk, const float* __restrict__ zbk,
    const float* __restrict__ Sk0, const float* __restrict__ Sk1,
    const float* __restrict__ biask, u16* __restrict__ Ck,
    float* __restrict__ tkmn, float* __restrict__ tkmx,
    const i8* __restrict__ Bv, const float* __restrict__ sbv, const float* __restrict__ zbv,
    const float* __restrict__ Sv0, const float* __restrict__ Sv1,
    const float* __restrict__ biasv, u16* __restrict__ Cv,
    float* __restrict__ tvmn, float* __restrict__ tvmx) {
  __shared__ __align__(16) i8 As[2 * 128 * 64], Bs[2 * 128 * 64];
  int bx, by; xcd_swz(bx, by);
  const int which = bx >> 4;
  const int bn = (bx & 15) * 128;
  const int bm = by * 128;
  const i8* B = (which == 0) ? Bq : (which == 1) ? Bk : Bv;
  const float* sb = (which == 0) ? sbq : (which == 1) ? sbk : sbv;
  const float* zb = (which == 0) ? zbq : (which == 1) ? zbk : zbv;
  const float* Sb0 = (which == 0) ? Sq0 : (which == 1) ? Sk0 : Sv0;
  const float* Sb1 = (which == 0) ? Sq1 : (which == 1) ? Sk1 : Sv1;
  const float* bias = (which == 0) ? biasq : (which == 1) ? biask : biasv;
  u16* C = (which == 0) ? Cq : (which == 1) ? Ck : Cv;
  float* tmn = (which == 0) ? tqmn : (which == 1) ? tkmn : tvmn;
  float* tmx = (which == 0) ? tqmx : (which == 1) ? tkmx : tvmx;
  const float alpha = (which == 0) ? 0.125f : 1.0f;

  i32x4 acc[4][4] = {};
  gemm128_i8_db(A, B, D_DIM, bm, bn, 0, D_DIM, As, Bs, acc);

  const int tid = threadIdx.x;
  const int wid = tid >> 6, lane = tid & 63;
  const int wr = wid >> 1, wc = wid & 1;
  const int lr = lane & 15, lk = lane >> 4;
  const int col0 = bn + wc * 64 + lr;
  const int rbase = bm + wr * 64 + lk * 4;
  const int tci = (bn >> 6) + wc;     // NT = 32
  float sbc[4], zbc[4], Sbc[4], bc[4];
#pragma unroll
  for (int ni = 0; ni < 4; ++ni) {
    const int col = col0 + ni * 16;
    sbc[ni] = sb[col]; zbc[ni] = zb[col];
    Sbc[ni] = Sb0[col] + Sb1[col]; bc[ni] = bias[col];
  }
#pragma unroll
  for (int mi = 0; mi < 4; ++mi) {
#pragma unroll
    for (int r = 0; r < 4; ++r) {
      const int row = rbase + mi * 16 + r;
      const float sar = sx[row], zar = zx[row];
      const float Sar = Sx0[row] + Sx1[row];
      float v[4];
#pragma unroll
      for (int ni = 0; ni < 4; ++ni) {
        float ci = (float)acc[mi][ni][r] + zar * Sbc[ni] + zbc[ni] * Sar +
                   2048.0f * zar * zbc[ni];
        v[ni] = (sar * sbc[ni] * ci + bc[ni]) * alpha;
      }
#pragma unroll
      for (int ni = 0; ni < 4; ++ni)
        C[(size_t)row * D_DIM + col0 + ni * 16] = f32_to_bf16_rne(v[ni]);
      float mnv = fminf(fminf(v[0], v[1]), fminf(v[2], v[3]));
      float mxv = fmaxf(fmaxf(v[0], v[1]), fmaxf(v[2], v[3]));
      mnv = fminf(mnv, __shfl_xor(mnv, 1, 64)); mxv = fmaxf(mxv, __shfl_xor(mxv, 1, 64));
      mnv = fminf(mnv, __shfl_xor(mnv, 2, 64)); mxv = fmaxf(mxv, __shfl_xor(mxv, 2, 64));
      mnv = fminf(mnv, __shfl_xor(mnv, 4, 64)); mxv = fmaxf(mxv, __shfl_xor(mxv, 4, 64));
      mnv = fminf(mnv, __shfl_xor(mnv, 8, 64)); mxv = fmaxf(mxv, __shfl_xor(mxv, 8, 64));
      if (lr == 0) {
        tmn[(size_t)row * 32 + tci] = mnv;
        tmx[(size_t)row * 32 + tci] = mxv;
      }
    }
  }
}

// ---- W1 (i8): relu epilogue; 4 blocks/CU ----
__global__ __launch_bounds__(256, 4) void gemm_w1_i8(
    const i8* __restrict__ A, const float* __restrict__ sx, const float* __restrict__ zx,
    const float* __restrict__ Sx0, const float* __restrict__ Sx1,
    const i8* __restrict__ B, const float* __restrict__ sb, const float* __restrict__ zb,
    const float* __restrict__ Sb0, const float* __restrict__ Sb1,
    const float* __restrict__ bias, u16* __restrict__ C, float* __restrict__ tmx) {
  __shared__ __align__(16) i8 As[2 * 128 * 64], Bs[2 * 128 * 64];
  int bx, by; xcd_swz(bx, by);
  const int bn = bx * 128, bm = by * 128;

  i32x4 acc[4][4] = {};
  gemm128_i8_db(A, B, D_DIM, bm, bn, 0, D_DIM, As, Bs, acc);

  const int tid = threadIdx.x;
  const int wid = tid >> 6, lane = tid & 63;
  const int wr = wid >> 1, wc = wid & 1;
  const int lr = lane & 15, lk = lane >> 4;
  const int col0 = bn + wc * 64 + lr;
  const int rbase = bm + wr * 64 + lk * 4;
  const int tci = (bn >> 6) + wc;     // NT = 128
  float sbc[4], zbc[4], Sbc[4], bc[4];
#pragma unroll
  for (int ni = 0; ni < 4; ++ni) {
    const int col = col0 + ni * 16;
    sbc[ni] = sb[col]; zbc[ni] = zb[col];
    Sbc[ni] = Sb0[col] + Sb1[col]; bc[ni] = bias[col];
  }
#pragma unroll
  for (int mi = 0; mi < 4; ++mi) {
#pragma unroll
    for (int r = 0; r < 4; ++r) {
      const int row = rbase + mi * 16 + r;
      const float sar = sx[row], zar = zx[row];
      const float Sar = Sx0[row] + Sx1[row];
      float v[4];
#pragma unroll
      for (int ni = 0; ni < 4; ++ni) {
        float ci = (float)acc[mi][ni][r] + zar * Sbc[ni] + zbc[ni] * Sar +
                   2048.0f * zar * zbc[ni];
        v[ni] = fmaxf(sar * sbc[ni] * ci + bc[ni], 0.f);
      }
#pragma unroll
      for (int ni = 0; ni < 4; ++ni)
        C[(size_t)row * FF_DIM + col0 + ni * 16] = f32_to_bf16_rne(v[ni]);
      float mxv = fmaxf(fmaxf(v[0], v[1]), fmaxf(v[2], v[3]));
      mxv = fmaxf(mxv, __shfl_xor(mxv, 1, 64));
      mxv = fmaxf(mxv, __shfl_xor(mxv, 2, 64));
      mxv = fmaxf(mxv, __shfl_xor(mxv, 4, 64));
      mxv = fmaxf(mxv, __shfl_xor(mxv, 8, 64));
      if (lr == 0) tmx[(size_t)row * 128 + tci] = mxv;
    }
  }
}

// ---- split-K partial (i8): raw acc only ----
__global__ __launch_bounds__(256, 4) void gemm_splitk_i8(
    const i8* __restrict__ A, const i8* __restrict__ B,
    float* __restrict__ part, int K, int nsplit) {
  __shared__ __align__(16) i8 As[2 * 128 * 64], Bs[2 * 128 * 64];
  int bx, by; xcd_swz(bx, by);
  const int bm = by * 128, bn = bx * 128;
  const int ks = blockIdx.z;
  const int kchunk = K / nsplit;
  i32x4 acc[4][4] = {};
  gemm128_i8_db(A, B, K, bm, bn, ks * kchunk, (ks + 1) * kchunk, As, Bs, acc);

  float* dst = part + (size_t)ks * S_LEN * D_DIM;
  const int tid = threadIdx.x;
  const int wid = tid >> 6, lane = tid & 63;
  const int wr = wid >> 1, wc = wid & 1;
  const int lr = lane & 15, lk = lane >> 4;
  const int col0 = bn + wc * 64 + lr;
  const int rbase = bm + wr * 64 + lk * 4;
#pragma unroll
  for (int ni = 0; ni < 4; ++ni) {
    const int col = col0 + ni * 16;
#pragma unroll
    for (int mi = 0; mi < 4; ++mi)
#pragma unroll
      for (int r = 0; r < 4; ++r)
        dst[(size_t)(rbase + mi * 16 + r) * D_DIM + col] = (float)acc[mi][ni][r];
  }
}

// ---- reduce of 4 raw partials + full zero-point correction + bias (+res) ----
__global__ __launch_bounds__(256) void splitk_reduce4(
    const float* __restrict__ part,
    const float* __restrict__ sxa, const float* __restrict__ zxa,
    const float* __restrict__ Sxa0, const float* __restrict__ Sxa1,
    const float* __restrict__ sw, const float* __restrict__ zw,
    const float* __restrict__ Sw0, const float* __restrict__ Sw1,
    float Kf, const float* __restrict__ bias, const float* __restrict__ res,
    float* __restrict__ out) {
  const size_t st4 = (size_t)S_LEN * D_DIM / 4;
  for (size_t i = (size_t)blockIdx.x * 256 + threadIdx.x; i < st4;
       i += (size_t)gridDim.x * 256) {
    const int row = (int)(i >> 9);
    const int c4 = (int)(i & 511);
    float4 s = ((const float4*)part)[i];
    float4 p1 = ((const float4*)part)[i + st4];
    float4 p2 = ((const float4*)part)[i + 2 * st4];
    float4 p3 = ((const float4*)part)[i + 3 * st4];
    s.x += p1.x + p2.x + p3.x; s.y += p1.y + p2.y + p3.y;
    s.z += p1.z + p2.z + p3.z; s.w += p1.w + p2.w + p3.w;
    const float sxr = sxa[row], zxr = zxa[row];
    const float Sxr = Sxa0[row] + Sxa1[row];
    float4 ws = ((const float4*)sw)[c4];
    float4 wz = ((const float4*)zw)[c4];
    float4 w0 = ((const float4*)Sw0)[c4];
    float4 w1 = ((const float4*)Sw1)[c4];
    float4 b4 = ((const float4*)bias)[c4];
    float4 o;
    o.x = sxr * ws.x * (s.x + zxr * (w0.x + w1.x) + wz.x * Sxr + Kf * zxr * wz.x) + b4.x;
    o.y = sxr * ws.y * (s.y + zxr * (w0.y + w1.y) + wz.y * Sxr + Kf * zxr * wz.y) + b4.y;
    o.z = sxr * ws.z * (s.z + zxr * (w0.z + w1.z) + wz.z * Sxr + Kf * zxr * wz.z) + b4.z;
    o.w = sxr * ws.w * (s.w + zxr * (w0.w + w1.w) + wz.w * Sxr + Kf * zxr * wz.w) + b4.w;
    if (res) {
      float4 r = ((const float4*)res)[i];
      o.x += r.x; o.y += r.y; o.z += r.z; o.w += r.w;
    }
    ((float4*)out)[i] = o;
  }
}

// ---- fused: h2 = corrected(sum parts)+bias+res; LN; quant -> i8 + NEW params ----
__global__ __launch_bounds__(256) void splitk_reduce_ln(
    const float* __restrict__ part,
    const float* __restrict__ sxa, const float* __restrict__ zxa,
    const float* __restrict__ Sxa0, const float* __restrict__ Sxa1,
    const float* __restrict__ sw, const float* __restrict__ zw,
    const float* __restrict__ Sw0, const float* __restrict__ Sw1,
    const float* __restrict__ bias, const float* __restrict__ res,
    float* __restrict__ h2out,
    const float* __restrict__ g, const float* __restrict__ bvec,
    i8* __restrict__ out, float* __restrict__ srow, float* __restrict__ zrow,
    float* __restrict__ S0row, float* __restrict__ S1row) {
  __shared__ float red[8];
  const int row = blockIdx.x, tid = threadIdx.x;
  const size_t st = (size_t)S_LEN * D_DIM;
  const float4* p0 = (const float4*)(part + (size_t)row * D_DIM);
  const float4* p1 = (const float4*)(part + st + (size_t)row * D_DIM);
  const float4* p2 = (const float4*)(part + 2 * st + (size_t)row * D_DIM);
  const float4* p3 = (const float4*)(part + 3 * st + (size_t)row * D_DIM);
  const float4* rr = (const float4*)(res + (size_t)row * D_DIM);
  const float4* b4 = (const float4*)bias;
  const float4* g4 = (const float4*)g;
  const float4* e4 = (const float4*)bvec;

  const float sxr = sxa[row], zxr = zxa[row];
  const float Sxr = Sxa0[row] + Sxa1[row];

  float4 v0, v1;
#pragma unroll
  for (int h = 0; h < 2; ++h) {
    const int idx = tid + h * 256;
    float4 a = p0[idx], q = p1[idx], u = p2[idx], w = p3[idx];
    float4 ws = ((const float4*)sw)[idx];
    float4 wz = ((const float4*)zw)[idx];
    float4 s0 = ((const float4*)Sw0)[idx];
    float4 s1 = ((const float4*)Sw1)[idx];
    float4 bb = b4[idx], rv = rr[idx];
    float4 o;
    o.x = sxr * ws.x * (a.x + q.x + u.x + w.x + zxr * (s0.x + s1.x) + wz.x * Sxr + 2048.0f * zxr * wz.x) + bb.x + rv.x;
    o.y = sxr * ws.y * (a.y + q.y + u.y + w.y + zxr * (s0.y + s1.y) + wz.y * Sxr + 2048.0f * zxr * wz.y) + bb.y + rv.y;
    o.z = sxr * ws.z * (a.z + q.z + u.z + w.z + zxr * (s0.z + s1.z) + wz.z * Sxr + 2048.0f * zxr * wz.z) + bb.z + rv.z;
    o.w = sxr * ws.w * (a.w + q.w + u.w + w.w + zxr * (s0.w + s1.w) + wz.w * Sxr + 2048.0f * zxr * wz.w) + bb.w + rv.w;
    if (h == 0) v0 = o; else v1 = o;
  }
  float* h2r = h2out + (size_t)row * D_DIM;
  *(float4*)&h2r[tid * 4] = v0;
  *(float4*)&h2r[1024 + tid * 4] = v1;

  float s = v0.x + v0.y + v0.z + v0.w + v1.x + v1.y + v1.z + v1.w;
  float ss = v0.x * v0.x + v0.y * v0.y + v0.z * v0.z + v0.w * v0.w +
             v1.x * v1.x + v1.y * v1.y + v1.z * v1.z + v1.w * v1.w;
  s = wred_sum(s); ss = wred_sum(ss);
  if ((tid & 63) == 0) { red[tid >> 6] = s; red[4 + (tid >> 6)] = ss; }
  __syncthreads();
  float mu = (red[0] + red[1] + red[2] + red[3]) / (float)D_DIM;
  float var = (red[4] + red[5] + red[6] + red[7]) / (float)D_DIM - mu * mu;
  float rstd = 1.0f / sqrtf(var + 1e-5f);
  __syncthreads();

  float mn = 0.f, mx = 0.f;
  float4 n0, n1;
  {
    float4 gg = g4[tid], bb = e4[tid];
    n0.x = (v0.x - mu) * rstd * gg.x + bb.x; n0.y = (v0.y - mu) * rstd * gg.y + bb.y;
    n0.z = (v0.z - mu) * rstd * gg.z + bb.z; n0.w = (v0.w - mu) * rstd * gg.w + bb.w;
    gg = g4[tid + 256]; bb = e4[tid + 256];
    n1.x = (v1.x - mu) * rstd * gg.x + bb.x; n1.y = (v1.y - mu) * rstd * gg.y + bb.y;
    n1.z = (v1.z - mu) * rstd * gg.z + bb.z; n1.w = (v1.w - mu) * rstd * gg.w + bb.w;
    mn = fminf(mn, fminf(fminf(n0.x, n0.y), fminf(n0.z, n0.w)));
    mn = fminf(mn, fminf(fminf(n1.x, n1.y), fminf(n1.z, n1.w)));
    mx = fmaxf(mx, fmaxf(fmaxf(n0.x, n0.y), fmaxf(n0.z, n0.w)));
    mx = fmaxf(mx, fmaxf(fmaxf(n1.x, n1.y), fmaxf(n1.z, n1.w)));
  }
  mn = wred_min(mn); mx = wred_max(mx);
  if ((tid & 63) == 0) { red[tid >> 6] = mn; red[4 + (tid >> 6)] = mx; }
  __syncthreads();
  mn = fminf(fminf(red[0], red[1]), fminf(red[2], red[3]));
  mx = fmaxf(fmaxf(red[4], red[5]), fmaxf(red[6], red[7]));
  float scale = fmaxf((mx - mn) / QMAX, 1e-5f);
  float zp = rintf(-mn / scale);
  if (tid == 0) { srow[row] = scale; zrow[row] = 128.0f - zp; }
  float q00 = fminf(fmaxf(rintf(n0.x / scale) + zp, 0.f), QMAX);
  float q01 = fminf(fmaxf(rintf(n0.y / scale) + zp, 0.f), QMAX);
  float q02 = fminf(fmaxf(rintf(n0.z / scale) + zp, 0.f), QMAX);
  float q03 = fminf(fmaxf(rintf(n0.w / scale) + zp, 0.f), QMAX);
  float q10 = fminf(fmaxf(rintf(n1.x / scale) + zp, 0.f), QMAX);
  float q11 = fminf(fmaxf(rintf(n1.y / scale) + zp, 0.f), QMAX);
  float q12 = fminf(fmaxf(rintf(n1.z / scale) + zp, 0.f), QMAX);
  float q13 = fminf(fmaxf(rintf(n1.w / scale) + zp, 0.f), QMAX);
  *(int*)&out[(size_t)row * D_DIM + tid * 4] = pack4_i8(q00, q01, q02, q03);
  *(int*)&out[(size_t)row * D_DIM + 1024 + tid * 4] = pack4_i8(q10, q11, q12, q13);
  float s0 = q00 + q01 + q02 + q03 - 512.f;
  float s1 = q10 + q11 + q12 + q13 - 512.f;
  __syncthreads();
  s0 = wred_sum(s0); s1 = wred_sum(s1);
  if ((tid & 63) == 0) { red[tid >> 6] = s0; red[4 + (tid >> 6)] = s1; }
  __syncthreads();
  if (tid == 0) {
    S0row[row] = red[0] + red[1] + red[2] + red[3];
    S1row[row] = red[4] + red[5] + red[6] + red[7];
  }
}

// ---- attention pass A: per-row max (t-units) + denom. LDS = Ks only (9 KB). ----
// head-major XCD chunking: each XCD owns ~4 heads (K/V L2-resident), heavy-first within head
__global__ __launch_bounds__(256) void attn_ml(
    const u16* __restrict__ qi, const float* __restrict__ sq,
    const u16* __restrict__ ki, const float* __restrict__ sk,
    float* __restrict__ Mb, float* __restrict__ Lb) {
  __shared__ __align__(16) u16 Ks[64][72];
  const int bid = blockIdx.x;
  const int swzb = (bid & 7) * ((S_LEN / 64 * H_NUM) >> 3) + (bid >> 3);
  const int h = swzb >> 5;
  const int ti = (S_LEN / 64 - 1) - (swzb & 31);
  const int i0 = ti * 64;
  const int tid = threadIdx.x;
  const int wid = tid >> 6, lane = tid & 63;
  const int lr = lane & 15, g = lane >> 4;
  const size_t hbase = (size_t)h * HD_DIM;

  const int r_a = tid >> 3, ch_a = tid & 7;
  const int r_b = 32 + r_a;

  const bf16x8 aq0 = *(const bf16x8*)&qi[(size_t)(i0 + wid * 16 + lr) * D_DIM + hbase + g * 8];
  const bf16x8 aq1 = *(const bf16x8*)&qi[(size_t)(i0 + wid * 16 + lr) * D_DIM + hbase + 32 + g * 8];
  float sq2[4];
#pragma unroll
  for (int r = 0; r < 4; ++r) sq2[r] = sq[i0 + wid * 16 + g * 4 + r] * LOG2E;

  const int ntiles = i0 / 64 + 1;
  float m_r[4] = {-1e30f, -1e30f, -1e30f, -1e30f};
  float l_r[4] = {0.f, 0.f, 0.f, 0.f};

  float4 ka0 = *(const float4*)&ki[(size_t)r_a * D_DIM + hbase + ch_a * 8];
  float4 ka1 = *(const float4*)&ki[(size_t)r_b * D_DIM + hbase + ch_a * 8];
  for (int t = 0; t < ntiles; ++t) {
    __syncthreads();
    *(float4*)&Ks[r_a][ch_a * 8] = ka0;
    *(float4*)&Ks[r_b][ch_a * 8] = ka1;
    __syncthreads();
    if (t + 1 < ntiles) {
      const int jn = (t + 1) * 64;
      ka0 = *(const float4*)&ki[(size_t)(jn + r_a) * D_DIM + hbase + ch_a * 8];
      ka1 = *(const float4*)&ki[(size_t)(jn + r_b) * D_DIM + hbase + ch_a * 8];
    }

    f32x4 accs[4] = {};
#pragma unroll
    for (int ni = 0; ni < 4; ++ni) {
      bf16x8 b0 = *(const bf16x8*)&Ks[ni * 16 + lr][g * 8];
      bf16x8 b1 = *(const bf16x8*)&Ks[ni * 16 + lr][32 + g * 8];
      accs[ni] = __builtin_amdgcn_mfma_f32_16x16x32_bf16(aq0, b0, accs[ni], 0, 0, 0);
      accs[ni] = __builtin_amdgcn_mfma_f32_16x16x32_bf16(aq1, b1, accs[ni], 0, 0, 0);
    }

    const int jt = t * 64;
    float tv[4][4];
#pragma unroll
    for (int ni = 0; ni < 4; ++ni) {
      const float skc = sk[jt + ni * 16 + lr];
#pragma unroll
      for (int r = 0; r < 4; ++r) tv[ni][r] = accs[ni][r] * sq2[r] * skc;
    }
    if (t == ntiles - 1) {
      const int jcol = jt + lr, irow = i0 + wid * 16 + g * 4;
#pragma unroll
      for (int ni = 0; ni < 4; ++ni)
#pragma unroll
        for (int r = 0; r < 4; ++r)
          if (jcol + ni * 16 > irow + r) tv[ni][r] = -1e30f;
    }
#pragma unroll
    for (int r = 0; r < 4; ++r) {
      float tmax = fmaxf(fmaxf(tv[0][r], tv[1][r]), fmaxf(tv[2][r], tv[3][r]));
      tmax = fmaxf(tmax, __shfl_xor(tmax, 1, 64));
      tmax = fmaxf(tmax, __shfl_xor(tmax, 2, 64));
      tmax = fmaxf(tmax, __shfl_xor(tmax, 4, 64));
      tmax = fmaxf(tmax, __shfl_xor(tmax, 8, 64));
      float mnew = fmaxf(m_r[r], tmax);
      float sum = exp2f(tv[0][r] - mnew) + exp2f(tv[1][r] - mnew) +
                  exp2f(tv[2][r] - mnew) + exp2f(tv[3][r] - mnew);
      sum += __shfl_xor(sum, 1, 64);
      sum += __shfl_xor(sum, 2, 64);
      sum += __shfl_xor(sum, 4, 64);
      sum += __shfl_xor(sum, 8, 64);
      l_r[r] = l_r[r] * exp2f(m_r[r] - mnew) + sum;
      m_r[r] = mnew;
    }
  }

  if (lr == 0) {
#pragma unroll
    for (int r = 0; r < 4; ++r) {
      const int row = i0 + wid * 16 + g * 4 + r;
      Mb[(size_t)h * S_LEN + row] = m_r[r];   // t-units (log2 domain)
      Lb[(size_t)h * S_LEN + row] = l_r[r];
    }
  }
}

// ---- attention pass B: quantized probs @ V. LDS = Ks+Ps+Vt (27 KB). ----
__global__ __launch_bounds__(256) void attn_pv(
    const u16* __restrict__ qi, const float* __restrict__ sq,
    const u16* __restrict__ ki, const float* __restrict__ sk,
    const u16* __restrict__ vt,   // per-head V^T: [H][64][S]
    const float* __restrict__ Mb, const float* __restrict__ Lb,
    float* __restrict__ ctx) {
  __shared__ __align__(16) u16 Ks[64][72];
  __shared__ __align__(16) u16 Ps[64][72];
  __shared__ __align__(16) u16 Vt[64][72];
  const int bid = blockIdx.x;
  const int swzb = (bid & 7) * ((S_LEN / 64 * H_NUM) >> 3) + (bid >> 3);
  const int h = swzb >> 5;
  const int ti = (S_LEN / 64 - 1) - (swzb & 31);
  const int i0 = ti * 64;
  const int tid = threadIdx.x;
  const int wid = tid >> 6, lane = tid & 63;
  const int lr = lane & 15, g = lane >> 4;
  const size_t hbase = (size_t)h * HD_DIM;
  const size_t vtbase = (size_t)h * HD_DIM * S_LEN;

  const int r_a = tid >> 3, ch_a = tid & 7;
  const int r_b = 32 + r_a;

  const bf16x8 aq0 = *(const bf16x8*)&qi[(size_t)(i0 + wid * 16 + lr) * D_DIM + hbase + g * 8];
  const bf16x8 aq1 = *(const bf16x8*)&qi[(size_t)(i0 + wid * 16 + lr) * D_DIM + hbase + 32 + g * 8];

  float sq2[4], b_r[4], qsc[4];
#pragma unroll
  for (int r = 0; r < 4; ++r) {
    const int row = i0 + wid * 16 + g * 4 + r;
    sq2[r] = sq[row] * LOG2E;
    float m_t = Mb[(size_t)h * S_LEN + row];
    float li = Lb[(size_t)h * S_LEN + row];
    float sc = fmaxf((1.0f / li) / QMAX, 1e-5f);
    qsc[r] = sc;
    b_r[r] = m_t - log2f(1.0f / (li * sc));   // q8 = rint(exp2(t - b_r))
  }

  const int ntiles = i0 / 64 + 1;
  f32x4 acco[4] = {};
  float4 kb0 = *(const float4*)&ki[(size_t)r_a * D_DIM + hbase + ch_a * 8];
  float4 kb1 = *(const float4*)&ki[(size_t)r_b * D_DIM + hbase + ch_a * 8];
  float4 vb0 = *(const float4*)&vt[vtbase + (size_t)r_a * S_LEN + ch_a * 8];
  float4 vb1 = *(const float4*)&vt[vtbase + (size_t)r_b * S_LEN + ch_a * 8];
  for (int t = 0; t < ntiles; ++t) {
    __syncthreads();
    *(float4*)&Ks[r_a][ch_a * 8] = kb0;
    *(float4*)&Ks[r_b][ch_a * 8] = kb1;
    *(float4*)&Vt[r_a][ch_a * 8] = vb0;
    *(float4*)&Vt[r_b][ch_a * 8] = vb1;
    __syncthreads();
    if (t + 1 < ntiles) {
      const int jn = (t + 1) * 64;
      kb0 = *(const float4*)&ki[(size_t)(jn + r_a) * D_DIM + hbase + ch_a * 8];
      kb1 = *(const float4*)&ki[(size_t)(jn + r_b) * D_DIM + hbase + ch_a * 8];
      vb0 = *(const float4*)&vt[vtbase + (size_t)r_a * S_LEN + jn + ch_a * 8];
      vb1 = *(const float4*)&vt[vtbase + (size_t)r_b * S_LEN + jn + ch_a * 8];
    }

    f32x4 accs[4] = {};
#pragma unroll
    for (int ni = 0; ni < 4; ++ni) {
      bf16x8 b0 = *(const bf16x8*)&Ks[ni * 16 + lr][g * 8];
      bf16x8 b1 = *(const bf16x8*)&Ks[ni * 16 + lr][32 + g * 8];
      accs[ni] = __builtin_amdgcn_mfma_f32_16x16x32_bf16(aq0, b0, accs[ni], 0, 0, 0);
      accs[ni] = __builtin_amdgcn_mfma_f32_16x16x32_bf16(aq1, b1, accs[ni], 0, 0, 0);
    }

    const int jt = t * 64;
    const bool diag = (t == ntiles - 1);
    const int jcol = jt + lr, irow = i0 + wid * 16 + g * 4;
#pragma unroll
    for (int ni = 0; ni < 4; ++ni) {
      const float skc = sk[jt + ni * 16 + lr];
#pragma unroll
      for (int r = 0; r < 4; ++r) {
        float tvv = accs[ni][r] * sq2[r] * skc;
        if (diag && (jcol + ni * 16 > irow + r)) tvv = -1e30f;
        float q8 = fminf(rintf(exp2f(tvv - b_r[r])), QMAX);   // exp2>=0
        Ps[wid * 16 + g * 4 + r][ni * 16 + lr] = f32i_to_bf16(q8);
      }
    }
    // Ps rows for this wave are wave-local: no barrier needed

    bf16x8 ap0 = *(const bf16x8*)&Ps[wid * 16 + lr][g * 8];
    bf16x8 ap1 = *(const bf16x8*)&Ps[wid * 16 + lr][32 + g * 8];
#pragma unroll
    for (int ni = 0; ni < 4; ++ni) {
      bf16x8 b0 = *(const bf16x8*)&Vt[ni * 16 + lr][g * 8];
      bf16x8 b1 = *(const bf16x8*)&Vt[ni * 16 + lr][32 + g * 8];
      acco[ni] = __builtin_amdgcn_mfma_f32_16x16x32_bf16(ap0, b0, acco[ni], 0, 0, 0);
      acco[ni] = __builtin_amdgcn_mfma_f32_16x16x32_bf16(ap1, b1, acco[ni], 0, 0, 0);
    }
  }

#pragma unroll
  for (int ni = 0; ni < 4; ++ni)
#pragma unroll
    for (int r = 0; r < 4; ++r) {
      const int row = i0 + wid * 16 + g * 4 + r;
      ctx[(size_t)row * D_DIM + hbase + ni * 16 + lr] = acco[ni][r] * qsc[r];
    }
}

extern "C" void kernel_launch(void* const* d_in, const int* in_sizes, int n_in,
                              void* d_out, int out_size, void* d_ws, size_t ws_size,
                              hipStream_t stream) {
  (void)in_sizes; (void)n_in; (void)out_size;
  const float* hs  = (const float*)d_in[0];
  const float* Wq  = (const float*)d_in[2];
  const float* bq  = (const float*)d_in[3];
  const float* Wk  = (const float*)d_in[4];
  const float* bk  = (const float*)d_in[5];
  const float* Wv  = (const float*)d_in[6];
  const float* bv  = (const float*)d_in[7];
  const float* Wo  = (const float*)d_in[8];
  const float* bo  = (const float*)d_in[9];
  const float* g1  = (const float*)d_in[10];
  const float* be1 = (const float*)d_in[11];
  const float* W1  = (const float*)d_in[12];
  const float* bf1 = (const float*)d_in[13];
  const float* W2  = (const float*)d_in[14];
  const float* bf2 = (const float*)d_in[15];
  const float* g2  = (const float*)d_in[16];
  const float* be2 = (const float*)d_in[17];
  float* out = (float*)d_out;

  const size_t SD = (size_t)S_LEN * D_DIM;
  const size_t SF = (size_t)S_LEN * FF_DIM;
  const size_t HS = (size_t)H_NUM * S_LEN;

  char* p = (char*)d_ws;
  auto alloc = [&](size_t bytes) { char* r = p; p += (bytes + 255) & ~(size_t)255; return r; };

  float* h2   = (float*)alloc(SD * 4);
  float* sx   = (float*)alloc(S_LEN * 4);
  float* zx   = (float*)alloc(S_LEN * 4);
  float* Sx0  = (float*)alloc(S_LEN * 4);
  float* Sx1  = (float*)alloc(S_LEN * 4);
  float* sy   = (float*)alloc(S_LEN * 4);
  float* zy   = (float*)alloc(S_LEN * 4);
  float* Sy0  = (float*)alloc(S_LEN * 4);
  float* Sy1  = (float*)alloc(S_LEN * 4);
  float* sxf  = (float*)alloc(S_LEN * 4);
  float* zxf  = (float*)alloc(S_LEN * 4);
  float* Sf0  = (float*)alloc(S_LEN * 4);
  float* Sf1  = (float*)alloc(S_LEN * 4);
  float* sqv  = (float*)alloc(S_LEN * 4);
  float* skv  = (float*)alloc(S_LEN * 4);
  float* Mb   = (float*)alloc(HS * 4);
  float* Lbv  = (float*)alloc(HS * 4);
  float* swq = (float*)alloc(D_DIM * 4); float* zwq = (float*)alloc(D_DIM * 4);
  float* Sq0 = (float*)alloc(D_DIM * 4); float* Sq1 = (float*)alloc(D_DIM * 4);
  float* swk = (float*)alloc(D_DIM * 4); float* zwk = (float*)alloc(D_DIM * 4);
  float* Sk0 = (float*)alloc(D_DIM * 4); float* Sk1 = (float*)alloc(D_DIM * 4);
  float* swv = (float*)alloc(D_DIM * 4); float* zwv = (float*)alloc(D_DIM * 4);
  float* Sv0 = (float*)alloc(D_DIM * 4); float* Sv1 = (float*)alloc(D_DIM * 4);
  float* swo = (float*)alloc(D_DIM * 4); float* zwo = (float*)alloc(D_DIM * 4);
  float* So0 = (float*)alloc(D_DIM * 4); float* So1 = (float*)alloc(D_DIM * 4);
  float* sw1 = (float*)alloc(FF_DIM * 4); float* zw1 = (float*)alloc(FF_DIM * 4);
  float* S10 = (float*)alloc(FF_DIM * 4); float* S11 = (float*)alloc(FF_DIM * 4);
  float* sw2 = (float*)alloc(D_DIM * 4); float* zw2 = (float*)alloc(D_DIM * 4);
  float* S20 = (float*)alloc(D_DIM * 4); float* S21 = (float*)alloc(D_DIM * 4);
  float* tqmn = (float*)alloc(S_LEN * 32 * 4);
  float* tqmx = (float*)alloc(S_LEN * 32 * 4);
  float* tkmn = (float*)alloc(S_LEN * 32 * 4);
  float* tkmx = (float*)alloc(S_LEN * 32 * 4);
  float* tvmn = (float*)alloc(S_LEN * 32 * 4);
  float* tvmx = (float*)alloc(S_LEN * 32 * 4);
  float* tf1x = (float*)alloc(S_LEN * 128 * 4);
  i8* xi  = (i8*)alloc(SD);
  i8* wqi = (i8*)alloc(SD);
  i8* wki = (i8*)alloc(SD);
  i8* wvi = (i8*)alloc(SD);
  i8* woi = (i8*)alloc(SD);
  i8* w1i = (i8*)alloc(SF);
  i8* w2i = (i8*)alloc(SF);
  i8* f1i = (i8*)alloc(SF);
  char* arena = alloc(8 * SD * 2);   // 64 MB, phase-aliased
  // phase QKV/attn:
  u16* qv   = (u16*)arena;                  // unit 0 (dead after requant3)
  u16* kv   = qv + SD;
  u16* vv   = kv + SD;
  u16* qi8  = vv + SD;
  u16* ki8  = qi8 + SD;
  u16* vfb  = ki8 + SD;
  float* ctxb = (float*)(vfb + SD);         // units 6-8
  u16* vtb  = qv;                           // V^T, aliases dead qv (unit 0)
  // phase Wo / W2: 4 x SD fp32 raw partials = whole arena
  float* pwo = (float*)arena;
  // phase FFN:
  u16* f1v = (u16*)arena;
  float* pw2 = (float*)arena;
  size_t need = (size_t)(p - (char*)d_ws);
  if (ws_size < need) return;

  dim3 blk(256);

  // all five K=2048 weights in one launch (grid 4*D + FF rows)
  wquantD_i8<<<4 * D_DIM + FF_DIM, blk, 0, stream>>>(
      Wq, wqi, swq, zwq, Sq0, Sq1,
      Wk, wki, swk, zwk, Sk0, Sk1,
      Wv, wvi, swv, zwv, Sv0, Sv1,
      Wo, woi, swo, zwo, So0, So1,
      W1, w1i, sw1, zw1, S10, S11);
  wquantW2_i8<<<D_DIM, blk, 0, stream>>>(W2, w2i, sw2, zw2, S20, S21);

  ln_quant_i8<<<S_LEN, blk, 0, stream>>>(hs, g1, be1, xi, sx, zx, Sx0, Sx1);

  dim3 gqkv(3 * D_DIM / 128, S_LEN / 128);
  gemm_qkv_i8<<<gqkv, blk, 0, stream>>>(xi, sx, zx, Sx0, Sx1,
                                        wqi, swq, zwq, Sq0, Sq1, bq, qv, tqmn, tqmx,
                                        wki, swk, zwk, Sk0, Sk1, bk, kv, tkmn, tkmx,
                                        wvi, swv, zwv, Sv0, Sv1, bv, vv, tvmn, tvmx);

  requant3<<<3 * S_LEN, blk, 0, stream>>>(qv, tqmn, tqmx, qi8, sqv,
                                          kv, tkmn, tkmx, ki8, skv,
                                          vv, tvmn, tvmx, vfb);

  dim3 gtv(S_LEN / 64, H_NUM);
  transpose_v<<<gtv, blk, 0, stream>>>(vfb, vtb);

  const int ga = (S_LEN / 64) * H_NUM;   // 1024 blocks
  attn_ml<<<ga, blk, 0, stream>>>(qi8, sqv, ki8, skv, Mb, Lbv);
  attn_pv<<<ga, blk, 0, stream>>>(qi8, sqv, ki8, skv, vtb, Mb, Lbv, ctxb);

  act_quant_i8<<<S_LEN, blk, 0, stream>>>(ctxb, xi, sx, zx, Sx0, Sx1);

  // Wo: split-K=4, raw partials; fused reduce + residual + LN2 + quant
  dim3 gwo(D_DIM / 128, S_LEN / 128, 4);
  gemm_splitk_i8<<<gwo, blk, 0, stream>>>(xi, woi, pwo, D_DIM, 4);
  splitk_reduce_ln<<<S_LEN, blk, 0, stream>>>(pwo, sx, zx, Sx0, Sx1,
                                              swo, zwo, So0, So1, bo, hs, h2,
                                              g2, be2, xi, sy, zy, Sy0, Sy1);

  dim3 gff(FF_DIM / 128, S_LEN / 128);
  gemm_w1_i8<<<gff, blk, 0, stream>>>(xi, sy, zy, Sy0, Sy1,
                                      w1i, sw1, zw1, S10, S11, bf1, f1v, tf1x);
  requant_ff_i8<<<S_LEN, blk, 0, stream>>>(f1v, tf1x, f1i, sxf, zxf, Sf0, Sf1);

  // W2: split-K=4, raw partials
  dim3 gw2(D_DIM / 128, S_LEN / 128, 4);
  gemm_splitk_i8<<<gw2, blk, 0, stream>>>(f1i, w2i, pw2, FF_DIM, 4);
  splitk_reduce4<<<2048, blk, 0, stream>>>(pw2, sxf, zxf, Sf0, Sf1,
                                           sw2, zw2, S20, S21, (float)FF_DIM,
                                           bf2, h2, out);
}

// Round 14
// 402.311 us; speedup vs baseline: 1.1637x; 1.1637x over previous
//
#include <hip/hip_runtime.h>
#include <hip/hip_bf16.h>
#include <math.h>

#define S_LEN 2048
#define D_DIM 2048
#define H_NUM 32
#define HD_DIM 64
#define FF_DIM 8192
#define QMAX 255.0f
#define LOG2E 1.4426950408889634f

typedef __attribute__((ext_vector_type(4))) float f32x4;
typedef __attribute__((ext_vector_type(4))) int i32x4;
typedef __attribute__((ext_vector_type(8))) __bf16 bf16x8;
typedef unsigned short u16;
typedef signed char i8;

__device__ __forceinline__ u16 f32i_to_bf16(float v) {
  return (u16)(__float_as_uint(v) >> 16);  // exact for ints in [-255,255]
}
__device__ __forceinline__ u16 f32_to_bf16_rne(float v) {
  __bf16 b = (__bf16)v;
  return *(u16*)&b;
}
__device__ __forceinline__ float bf16_to_f32(u16 u) {
  return __uint_as_float((unsigned int)u << 16);
}
__device__ __forceinline__ int pack4_i8(float q0, float q1, float q2, float q3) {
  int c0 = (int)q0 - 128, c1 = (int)q1 - 128, c2 = (int)q2 - 128, c3 = (int)q3 - 128;
  return (c0 & 0xFF) | ((c1 & 0xFF) << 8) | ((c2 & 0xFF) << 16) | ((c3 & 0xFF) << 24);
}

__device__ __forceinline__ float wred_sum(float v) {
#pragma unroll
  for (int o = 1; o < 64; o <<= 1) v += __shfl_xor(v, o, 64);
  return v;
}
__device__ __forceinline__ float wred_min(float v) {
#pragma unroll
  for (int o = 1; o < 64; o <<= 1) v = fminf(v, __shfl_xor(v, o, 64));
  return v;
}
__device__ __forceinline__ float wred_max(float v) {
#pragma unroll
  for (int o = 1; o < 64; o <<= 1) v = fmaxf(v, __shfl_xor(v, o, 64));
  return v;
}

__device__ __forceinline__ void gload_lds16(const void* g, void* l) {
  __builtin_amdgcn_global_load_lds(
      (__attribute__((address_space(1))) void*)(g),
      (__attribute__((address_space(3))) void*)(l), 16, 0, 0);
}

// bijective XCD-aware swizzle, COLUMN-major decode
__device__ __forceinline__ void xcd_swz(int& bx, int& by) {
  const int gy = gridDim.y;
  const int nwg = gridDim.x * gy;
  const int orig = blockIdx.y + gy * blockIdx.x;   // column-major index
  const int swz = (orig & 7) * (nwg >> 3) + (orig >> 3);
  by = swz % gy;
  bx = swz / gy;
}

// balanced attention block mapping: per-CU tile count is exactly constant (66)
// h = bid&31; a=(bid>>5)&7; b=bid>>8; ti in {31-a, a, 23-a, 8+a}
__device__ __forceinline__ void attn_map(int bid, int& h, int& ti) {
  h = bid & (H_NUM - 1);
  const int a = (bid >> 5) & 7;
  const int b = bid >> 8;
  ti = (b == 0) ? (31 - a) : (b == 1) ? a : (b == 2) ? (23 - a) : (8 + a);
}

// ---- LayerNorm + per-token quant -> i8 (q-128) + scale + z'(=128-zp) + half-sums ----
__global__ __launch_bounds__(256) void ln_quant_i8(const float* __restrict__ x,
                                                   const float* __restrict__ g,
                                                   const float* __restrict__ bvec,
                                                   i8* __restrict__ out,
                                                   float* __restrict__ srow,
                                                   float* __restrict__ zrow,
                                                   float* __restrict__ S0row,
                                                   float* __restrict__ S1row) {
  __shared__ float red[8];
  const int row = blockIdx.x, tid = threadIdx.x;
  const float4* xr = (const float4*)(x + (size_t)row * D_DIM);
  const float4* g4 = (const float4*)g;
  const float4* b4 = (const float4*)bvec;

  float4 v0 = xr[tid], v1 = xr[tid + 256];
  float s = v0.x + v0.y + v0.z + v0.w + v1.x + v1.y + v1.z + v1.w;
  float ss = v0.x * v0.x + v0.y * v0.y + v0.z * v0.z + v0.w * v0.w +
             v1.x * v1.x + v1.y * v1.y + v1.z * v1.z + v1.w * v1.w;
  s = wred_sum(s); ss = wred_sum(ss);
  if ((tid & 63) == 0) { red[tid >> 6] = s; red[4 + (tid >> 6)] = ss; }
  __syncthreads();
  float mu = (red[0] + red[1] + red[2] + red[3]) / (float)D_DIM;
  float var = (red[4] + red[5] + red[6] + red[7]) / (float)D_DIM - mu * mu;
  float rstd = 1.0f / sqrtf(var + 1e-5f);
  __syncthreads();

  float mn = 0.f, mx = 0.f;
  float4 n0, n1;
  {
    float4 gg = g4[tid], bb = b4[tid];
    n0.x = (v0.x - mu) * rstd * gg.x + bb.x; n0.y = (v0.y - mu) * rstd * gg.y + bb.y;
    n0.z = (v0.z - mu) * rstd * gg.z + bb.z; n0.w = (v0.w - mu) * rstd * gg.w + bb.w;
    gg = g4[tid + 256]; bb = b4[tid + 256];
    n1.x = (v1.x - mu) * rstd * gg.x + bb.x; n1.y = (v1.y - mu) * rstd * gg.y + bb.y;
    n1.z = (v1.z - mu) * rstd * gg.z + bb.z; n1.w = (v1.w - mu) * rstd * gg.w + bb.w;
    mn = fminf(mn, fminf(fminf(n0.x, n0.y), fminf(n0.z, n0.w)));
    mn = fminf(mn, fminf(fminf(n1.x, n1.y), fminf(n1.z, n1.w)));
    mx = fmaxf(mx, fmaxf(fmaxf(n0.x, n0.y), fmaxf(n0.z, n0.w)));
    mx = fmaxf(mx, fmaxf(fmaxf(n1.x, n1.y), fmaxf(n1.z, n1.w)));
  }
  mn = wred_min(mn); mx = wred_max(mx);
  if ((tid & 63) == 0) { red[tid >> 6] = mn; red[4 + (tid >> 6)] = mx; }
  __syncthreads();
  mn = fminf(fminf(red[0], red[1]), fminf(red[2], red[3]));
  mx = fmaxf(fmaxf(red[4], red[5]), fmaxf(red[6], red[7]));
  float scale = fmaxf((mx - mn) / QMAX, 1e-5f);
  float zp = rintf(-mn / scale);
  if (tid == 0) { srow[row] = scale; zrow[row] = 128.0f - zp; }

  float q00 = fminf(fmaxf(rintf(n0.x / scale) + zp, 0.f), QMAX);
  float q01 = fminf(fmaxf(rintf(n0.y / scale) + zp, 0.f), QMAX);
  float q02 = fminf(fmaxf(rintf(n0.z / scale) + zp, 0.f), QMAX);
  float q03 = fminf(fmaxf(rintf(n0.w / scale) + zp, 0.f), QMAX);
  float q10 = fminf(fmaxf(rintf(n1.x / scale) + zp, 0.f), QMAX);
  float q11 = fminf(fmaxf(rintf(n1.y / scale) + zp, 0.f), QMAX);
  float q12 = fminf(fmaxf(rintf(n1.z / scale) + zp, 0.f), QMAX);
  float q13 = fminf(fmaxf(rintf(n1.w / scale) + zp, 0.f), QMAX);
  *(int*)&out[(size_t)row * D_DIM + tid * 4] = pack4_i8(q00, q01, q02, q03);
  *(int*)&out[(size_t)row * D_DIM + 1024 + tid * 4] = pack4_i8(q10, q11, q12, q13);
  float s0 = q00 + q01 + q02 + q03 - 512.f;
  float s1 = q10 + q11 + q12 + q13 - 512.f;
  __syncthreads();
  s0 = wred_sum(s0); s1 = wred_sum(s1);
  if ((tid & 63) == 0) { red[tid >> 6] = s0; red[4 + (tid >> 6)] = s1; }
  __syncthreads();
  if (tid == 0) {
    S0row[row] = red[0] + red[1] + red[2] + red[3];
    S1row[row] = red[4] + red[5] + red[6] + red[7];
  }
}

// ---- fp32 ctx row -> quant -> i8 + params ----
__global__ __launch_bounds__(256) void act_quant_i8(const float* __restrict__ x,
                                                    i8* __restrict__ out,
                                                    float* __restrict__ srow,
                                                    float* __restrict__ zrow,
                                                    float* __restrict__ S0row,
                                                    float* __restrict__ S1row) {
  __shared__ float red[8];
  const int row = blockIdx.x, tid = threadIdx.x;
  const float4* xr = (const float4*)(x + (size_t)row * D_DIM);
  float4 n0 = xr[tid], n1 = xr[tid + 256];
  float mn = 0.f, mx = 0.f;
  mn = fminf(mn, fminf(fminf(n0.x, n0.y), fminf(n0.z, n0.w)));
  mn = fminf(mn, fminf(fminf(n1.x, n1.y), fminf(n1.z, n1.w)));
  mx = fmaxf(mx, fmaxf(fmaxf(n0.x, n0.y), fmaxf(n0.z, n0.w)));
  mx = fmaxf(mx, fmaxf(fmaxf(n1.x, n1.y), fmaxf(n1.z, n1.w)));
  mn = wred_min(mn); mx = wred_max(mx);
  if ((tid & 63) == 0) { red[tid >> 6] = mn; red[4 + (tid >> 6)] = mx; }
  __syncthreads();
  mn = fminf(fminf(red[0], red[1]), fminf(red[2], red[3]));
  mx = fmaxf(fmaxf(red[4], red[5]), fmaxf(red[6], red[7]));
  float scale = fmaxf((mx - mn) / QMAX, 1e-5f);
  float zp = rintf(-mn / scale);
  if (tid == 0) { srow[row] = scale; zrow[row] = 128.0f - zp; }
  float q00 = fminf(fmaxf(rintf(n0.x / scale) + zp, 0.f), QMAX);
  float q01 = fminf(fmaxf(rintf(n0.y / scale) + zp, 0.f), QMAX);
  float q02 = fminf(fmaxf(rintf(n0.z / scale) + zp, 0.f), QMAX);
  float q03 = fminf(fmaxf(rintf(n0.w / scale) + zp, 0.f), QMAX);
  float q10 = fminf(fmaxf(rintf(n1.x / scale) + zp, 0.f), QMAX);
  float q11 = fminf(fmaxf(rintf(n1.y / scale) + zp, 0.f), QMAX);
  float q12 = fminf(fmaxf(rintf(n1.z / scale) + zp, 0.f), QMAX);
  float q13 = fminf(fmaxf(rintf(n1.w / scale) + zp, 0.f), QMAX);
  *(int*)&out[(size_t)row * D_DIM + tid * 4] = pack4_i8(q00, q01, q02, q03);
  *(int*)&out[(size_t)row * D_DIM + 1024 + tid * 4] = pack4_i8(q10, q11, q12, q13);
  float s0 = q00 + q01 + q02 + q03 - 512.f;
  float s1 = q10 + q11 + q12 + q13 - 512.f;
  __syncthreads();
  s0 = wred_sum(s0); s1 = wred_sum(s1);
  if ((tid & 63) == 0) { red[tid >> 6] = s0; red[4 + (tid >> 6)] = s1; }
  __syncthreads();
  if (tid == 0) {
    S0row[row] = red[0] + red[1] + red[2] + red[3];
    S1row[row] = red[4] + red[5] + red[6] + red[7];
  }
}

// ---- single-pass K=2048 weight quant body (row fully register-cached) ----
__device__ __forceinline__ void wquantD_body(const float* __restrict__ wr0,
                                             i8* __restrict__ wo,
                                             float* __restrict__ sc,
                                             float* __restrict__ zc,
                                             float* __restrict__ S0c,
                                             float* __restrict__ S1c, int row) {
  __shared__ float red[8];
  const int tid = threadIdx.x;
  const float4* wr = (const float4*)wr0;
  float4 v0 = wr[tid], v1 = wr[tid + 256];
  float mn = 0.f, mx = 0.f;
  mn = fminf(mn, fminf(fminf(v0.x, v0.y), fminf(v0.z, v0.w)));
  mn = fminf(mn, fminf(fminf(v1.x, v1.y), fminf(v1.z, v1.w)));
  mx = fmaxf(mx, fmaxf(fmaxf(v0.x, v0.y), fmaxf(v0.z, v0.w)));
  mx = fmaxf(mx, fmaxf(fmaxf(v1.x, v1.y), fmaxf(v1.z, v1.w)));
  mn = wred_min(mn); mx = wred_max(mx);
  if ((tid & 63) == 0) { red[tid >> 6] = mn; red[4 + (tid >> 6)] = mx; }
  __syncthreads();
  mn = fminf(fminf(red[0], red[1]), fminf(red[2], red[3]));
  mx = fmaxf(fmaxf(red[4], red[5]), fmaxf(red[6], red[7]));
  float scale = fmaxf((mx - mn) / QMAX, 1e-5f);
  float zp = rintf(-mn / scale);
  if (tid == 0) { sc[row] = scale; zc[row] = 128.0f - zp; }
  float q00 = fminf(fmaxf(rintf(v0.x / scale) + zp, 0.f), QMAX);
  float q01 = fminf(fmaxf(rintf(v0.y / scale) + zp, 0.f), QMAX);
  float q02 = fminf(fmaxf(rintf(v0.z / scale) + zp, 0.f), QMAX);
  float q03 = fminf(fmaxf(rintf(v0.w / scale) + zp, 0.f), QMAX);
  float q10 = fminf(fmaxf(rintf(v1.x / scale) + zp, 0.f), QMAX);
  float q11 = fminf(fmaxf(rintf(v1.y / scale) + zp, 0.f), QMAX);
  float q12 = fminf(fmaxf(rintf(v1.z / scale) + zp, 0.f), QMAX);
  float q13 = fminf(fmaxf(rintf(v1.w / scale) + zp, 0.f), QMAX);
  *(int*)&wo[tid * 4] = pack4_i8(q00, q01, q02, q03);
  *(int*)&wo[1024 + tid * 4] = pack4_i8(q10, q11, q12, q13);
  float s0 = q00 + q01 + q02 + q03 - 512.f;
  float s1 = q10 + q11 + q12 + q13 - 512.f;
  __syncthreads();
  s0 = wred_sum(s0); s1 = wred_sum(s1);
  if ((tid & 63) == 0) { red[tid >> 6] = s0; red[4 + (tid >> 6)] = s1; }
  __syncthreads();
  if (tid == 0) {
    S0c[row] = red[0] + red[1] + red[2] + red[3];
    S1c[row] = red[4] + red[5] + red[6] + red[7];
  }
}

// five K=2048 weights in one launch
__global__ __launch_bounds__(256) void wquantD_i8(
    const float* __restrict__ Wq, i8* __restrict__ Oq, float* sq_, float* zq_, float* aq_, float* bq_,
    const float* __restrict__ Wk, i8* __restrict__ Ok, float* sk_, float* zk_, float* ak_, float* bk_,
    const float* __restrict__ Wv, i8* __restrict__ Ov, float* sv_, float* zv_, float* av_, float* bv_,
    const float* __restrict__ Wo, i8* __restrict__ Oo, float* so_, float* zo_, float* ao_, float* bo_,
    const float* __restrict__ W1, i8* __restrict__ O1, float* s1_, float* z1_, float* a1_, float* b1_) {
  const int b = blockIdx.x;
  int which, row;
  if (b < 4 * D_DIM) { which = b >> 11; row = b & (D_DIM - 1); }
  else { which = 4; row = b - 4 * D_DIM; }
  const float* W = (which == 0) ? Wq : (which == 1) ? Wk : (which == 2) ? Wv : (which == 3) ? Wo : W1;
  i8* O = (which == 0) ? Oq : (which == 1) ? Ok : (which == 2) ? Ov : (which == 3) ? Oo : O1;
  float* sc = (which == 0) ? sq_ : (which == 1) ? sk_ : (which == 2) ? sv_ : (which == 3) ? so_ : s1_;
  float* zc = (which == 0) ? zq_ : (which == 1) ? zk_ : (which == 2) ? zv_ : (which == 3) ? zo_ : z1_;
  float* Sa = (which == 0) ? aq_ : (which == 1) ? ak_ : (which == 2) ? av_ : (which == 3) ? ao_ : a1_;
  float* Sb = (which == 0) ? bq_ : (which == 1) ? bk_ : (which == 2) ? bv_ : (which == 3) ? bo_ : b1_;
  wquantD_body(W + (size_t)row * D_DIM, O + (size_t)row * D_DIM, sc, zc, Sa, Sb, row);
}

// ---- single-pass K=8192 weight quant (W2) ----
__global__ __launch_bounds__(256) void wquantW2_i8(const float* __restrict__ W,
                                                   i8* __restrict__ Wi,
                                                   float* __restrict__ sc,
                                                   float* __restrict__ zc,
                                                   float* __restrict__ S0c,
                                                   float* __restrict__ S1c) {
  __shared__ float red[8];
  const int row = blockIdx.x, tid = threadIdx.x;
  const float4* wr = (const float4*)(W + (size_t)row * FF_DIM);
  float4 v[8];
#pragma unroll
  for (int j = 0; j < 8; ++j) v[j] = wr[tid + 256 * j];
  float mn = 0.f, mx = 0.f;
#pragma unroll
  for (int j = 0; j < 8; ++j) {
    mn = fminf(mn, fminf(fminf(v[j].x, v[j].y), fminf(v[j].z, v[j].w)));
    mx = fmaxf(mx, fmaxf(fmaxf(v[j].x, v[j].y), fmaxf(v[j].z, v[j].w)));
  }
  mn = wred_min(mn); mx = wred_max(mx);
  if ((tid & 63) == 0) { red[tid >> 6] = mn; red[4 + (tid >> 6)] = mx; }
  __syncthreads();
  mn = fminf(fminf(red[0], red[1]), fminf(red[2], red[3]));
  mx = fmaxf(fmaxf(red[4], red[5]), fmaxf(red[6], red[7]));
  float scale = fmaxf((mx - mn) / QMAX, 1e-5f);
  float zp = rintf(-mn / scale);
  if (tid == 0) { sc[row] = scale; zc[row] = 128.0f - zp; }
  float s0 = 0.f, s1 = 0.f;
#pragma unroll
  for (int j = 0; j < 8; ++j) {
    float q0 = fminf(fmaxf(rintf(v[j].x / scale) + zp, 0.f), QMAX);
    float q1 = fminf(fmaxf(rintf(v[j].y / scale) + zp, 0.f), QMAX);
    float q2 = fminf(fmaxf(rintf(v[j].z / scale) + zp, 0.f), QMAX);
    float q3 = fminf(fmaxf(rintf(v[j].w / scale) + zp, 0.f), QMAX);
    *(int*)&Wi[(size_t)row * FF_DIM + (tid + 256 * j) * 4] = pack4_i8(q0, q1, q2, q3);
    float gs = q0 + q1 + q2 + q3 - 512.f;
    if (j < 4) s0 += gs; else s1 += gs;
  }
  __syncthreads();
  s0 = wred_sum(s0); s1 = wred_sum(s1);
  if ((tid & 63) == 0) { red[tid >> 6] = s0; red[4 + (tid >> 6)] = s1; }
  __syncthreads();
  if (tid == 0) {
    S0c[row] = red[0] + red[1] + red[2] + red[3];
    S1c[row] = red[4] + red[5] + red[6] + red[7];
  }
}

// ---- requant q/k/v in one launch ----
__global__ __launch_bounds__(256) void requant3(
    const u16* __restrict__ qv, const float* __restrict__ tqmn, const float* __restrict__ tqmx,
    u16* __restrict__ qo, float* __restrict__ sqv,
    const u16* __restrict__ kv, const float* __restrict__ tkmn, const float* __restrict__ tkmx,
    u16* __restrict__ ko, float* __restrict__ skv,
    const u16* __restrict__ vv, const float* __restrict__ tvmn, const float* __restrict__ tvmx,
    u16* __restrict__ vo) {
  __shared__ float red[8];
  const int wh = blockIdx.x >> 11;
  const int row = blockIdx.x & (S_LEN - 1);
  const int tid = threadIdx.x;
  const u16* vals = (wh == 0) ? qv : (wh == 1) ? kv : vv;
  const float* tmn = (wh == 0) ? tqmn : (wh == 1) ? tkmn : tvmn;
  const float* tmx = (wh == 0) ? tqmx : (wh == 1) ? tkmx : tvmx;
  u16* out = (wh == 0) ? qo : (wh == 1) ? ko : vo;
  float* srow = (wh == 0) ? sqv : (wh == 1) ? skv : nullptr;
  const int value_mode = (wh == 2) ? 1 : 0;

  float mn = 0.f, mx = 0.f;
  if (tid < 32) {
    mn = tmn[(size_t)row * 32 + tid];
    mx = tmx[(size_t)row * 32 + tid];
  }
  mn = wred_min(mn); mx = wred_max(mx);
  if ((tid & 63) == 0) { red[tid >> 6] = mn; red[4 + (tid >> 6)] = mx; }
  __syncthreads();
  mn = fminf(fminf(red[0], red[1]), fminf(red[2], red[3]));
  mx = fmaxf(fmaxf(red[4], red[5]), fmaxf(red[6], red[7]));
  mn = fminf(mn, 0.f); mx = fmaxf(mx, 0.f);
  float scale = fmaxf((mx - mn) / QMAX, 1e-5f);
  float zp = rintf(-mn / scale);
  if (srow && tid == 0) srow[row] = scale;
  const ushort4* vr = (const ushort4*)(vals + (size_t)row * D_DIM);
  ushort4* orow = (ushort4*)(out + (size_t)row * D_DIM);
  for (int i = tid; i < D_DIM / 4; i += 256) {
    ushort4 u = vr[i];
    float q0 = fminf(fmaxf(rintf(bf16_to_f32(u.x) / scale) + zp, 0.f), QMAX) - zp;
    float q1 = fminf(fmaxf(rintf(bf16_to_f32(u.y) / scale) + zp, 0.f), QMAX) - zp;
    float q2 = fminf(fmaxf(rintf(bf16_to_f32(u.z) / scale) + zp, 0.f), QMAX) - zp;
    float q3 = fminf(fmaxf(rintf(bf16_to_f32(u.w) / scale) + zp, 0.f), QMAX) - zp;
    ushort4 o;
    if (value_mode) {
      o.x = f32_to_bf16_rne(q0 * scale); o.y = f32_to_bf16_rne(q1 * scale);
      o.z = f32_to_bf16_rne(q2 * scale); o.w = f32_to_bf16_rne(q3 * scale);
    } else {
      o.x = f32i_to_bf16(q0); o.y = f32i_to_bf16(q1);
      o.z = f32i_to_bf16(q2); o.w = f32i_to_bf16(q3);
    }
    orow[i] = o;
  }
}

// ---- transpose fake-quant V: vfb[S][D] -> vtb [H][64][S] (per-head V^T) ----
__global__ __launch_bounds__(256) void transpose_v(const u16* __restrict__ vfb,
                                                   u16* __restrict__ vtb) {
  __shared__ u16 Ts[64][66];
  const int j0 = blockIdx.x * 64;
  const int h = blockIdx.y;
  const int tid = threadIdx.x;
  for (int c = tid; c < 512; c += 256) {
    int r = c >> 3, ch = c & 7;
    *(float4*)&Ts[r][ch * 8] =
        *(const float4*)&vfb[(size_t)(j0 + r) * D_DIM + h * HD_DIM + ch * 8];
  }
  __syncthreads();
  for (int c = tid; c < 512; c += 256) {
    int d = c >> 3, ch = c & 7;
    u16 tmp[8];
#pragma unroll
    for (int e = 0; e < 8; ++e) tmp[e] = Ts[ch * 8 + e][d];
    *(float4*)&vtb[(size_t)(h * HD_DIM + d) * S_LEN + j0 + ch * 8] = *(float4*)tmp;
  }
}

// ---- requant f1 (relu, zp=0) ----
__global__ __launch_bounds__(256) void requant_ff_i8(const u16* __restrict__ vals,
                                                     const float* __restrict__ tmx,
                                                     i8* __restrict__ out,
                                                     float* __restrict__ srow,
                                                     float* __restrict__ zrow,
                                                     float* __restrict__ S0row,
                                                     float* __restrict__ S1row) {
  __shared__ float red[8];
  const int row = blockIdx.x, tid = threadIdx.x;
  float mx = (tid < 128) ? tmx[(size_t)row * 128 + tid] : 0.f;
  mx = wred_max(mx);
  if ((tid & 63) == 0) red[tid >> 6] = mx;
  __syncthreads();
  mx = fmaxf(fmaxf(red[0], red[1]), fmaxf(red[2], red[3]));
  mx = fmaxf(mx, 0.f);
  float scale = fmaxf(mx / QMAX, 1e-5f);
  if (tid == 0) { srow[row] = scale; zrow[row] = 128.0f; }
  const ushort4* vr = (const ushort4*)(vals + (size_t)row * FF_DIM);
  const int N4 = FF_DIM >> 2;
  float s0 = 0.f, s1 = 0.f;
  for (int i = tid; i < N4; i += 256) {
    ushort4 u = vr[i];
    float q0 = fminf(fmaxf(rintf(bf16_to_f32(u.x) / scale), 0.f), QMAX);
    float q1 = fminf(fmaxf(rintf(bf16_to_f32(u.y) / scale), 0.f), QMAX);
    float q2 = fminf(fmaxf(rintf(bf16_to_f32(u.z) / scale), 0.f), QMAX);
    float q3 = fminf(fmaxf(rintf(bf16_to_f32(u.w) / scale), 0.f), QMAX);
    *(int*)&out[(size_t)row * FF_DIM + i * 4] = pack4_i8(q0, q1, q2, q3);
    float gs = q0 + q1 + q2 + q3 - 512.f;
    if (i < 1024) s0 += gs; else s1 += gs;
  }
  __syncthreads();
  s0 = wred_sum(s0); s1 = wred_sum(s1);
  if ((tid & 63) == 0) { red[tid >> 6] = s0; red[4 + (tid >> 6)] = s1; }
  __syncthreads();
  if (tid == 0) {
    S0row[row] = red[0] + red[1] + red[2] + red[3];
    S1row[row] = red[4] + red[5] + red[6] + red[7];
  }
}

// ---- i8 double-buffered 128x128x64 MFMA body ----
__device__ __forceinline__ void gemm128_i8_db(
    const i8* __restrict__ A, const i8* __restrict__ B,
    int K, int bm, int bn, int k_begin, int k_end,
    i8* As, i8* Bs, i32x4 (&acc)[4][4]) {
  const int tid = threadIdx.x;
  const int wid = tid >> 6, lane = tid & 63;
  const int wr = wid >> 1, wc = wid & 1;
  const int lr = lane & 15, lk = lane >> 4;
  const int r0 = tid >> 2, c0 = (tid & 3) * 16;
  const int r1 = 64 + r0;
  const size_t ldsb0 = (size_t)(wid * 64) * 16;
  const size_t ldsb1 = (size_t)(256 + wid * 64) * 16;

  const i8* Ag0 = A + (size_t)(bm + r0) * K + c0;
  const i8* Ag1 = A + (size_t)(bm + r1) * K + c0;
  const i8* Bg0 = B + (size_t)(bn + r0) * K + c0;
  const i8* Bg1 = B + (size_t)(bn + r1) * K + c0;

  const int nt = (k_end - k_begin) >> 6;

#define STAGE_I8(t)                                   \
  {                                                   \
    const int _k = k_begin + (t) * 64;                \
    i8* _Ab = As + (size_t)((t) & 1) * 8192;          \
    i8* _Bb = Bs + (size_t)((t) & 1) * 8192;          \
    gload_lds16(Ag0 + _k, _Ab + ldsb0);               \
    gload_lds16(Ag1 + _k, _Ab + ldsb1);               \
    gload_lds16(Bg0 + _k, _Bb + ldsb0);               \
    gload_lds16(Bg1 + _k, _Bb + ldsb1);               \
  }

  STAGE_I8(0);
  __syncthreads();

  for (int t = 0; t < nt; ++t) {
    const i8* Ac = As + (size_t)(t & 1) * 8192;
    const i8* Bc = Bs + (size_t)(t & 1) * 8192;
    i32x4 af[4], bf[4];
#pragma unroll
    for (int mi = 0; mi < 4; ++mi)
      af[mi] = *(const i32x4*)&Ac[(size_t)(wr * 64 + mi * 16 + lr) * 64 + lk * 16];
#pragma unroll
    for (int ni = 0; ni < 4; ++ni)
      bf[ni] = *(const i32x4*)&Bc[(size_t)(wc * 64 + ni * 16 + lr) * 64 + lk * 16];
    if (t + 1 < nt) STAGE_I8(t + 1);
#pragma unroll
    for (int mi = 0; mi < 4; ++mi)
#pragma unroll
      for (int ni = 0; ni < 4; ++ni)
        acc[mi][ni] = __builtin_amdgcn_mfma_i32_16x16x64_i8(af[mi], bf[ni], acc[mi][ni], 0, 0, 0);
    __syncthreads();
  }
#undef STAGE_I8
}

// ---- fused QKV (i8) ----
__global__ __launch_bounds__(256) void gemm_qkv_i8(
    const i8* __restrict__ A, const float* __restrict__ sx, const float* __restrict__ zx,
    const float* __restrict__ Sx0, const float* __restrict__ Sx1,
    const i8* __restrict__ Bq, const float* __restrict__ sbq, const float* __restrict__ zbq,
    const float* __restrict__ Sq0, const float* __restrict__ Sq1,
    const float* __restrict__ biasq, u16* __restrict__ Cq,
    float* __restrict__ tqmn, float* __restrict__ tqmx,
    const i8* __restrict__ Bk, const float* __restrict__ sbk, const float* __restrict__ zbk,
    const float* __restrict__ Sk0, const float* __restrict__ Sk1,
    const float* __restrict__ biask, u16* __restrict__ Ck,
    float* __restrict__ tkmn, float* __restrict__ tkmx,
    const i8* __restrict__ Bv, const float* __restrict__ sbv, const float* __restrict__ zbv,
    const float* __restrict__ Sv0, const float* __restrict__ Sv1,
    const float* __restrict__ biasv, u16* __restrict__ Cv,
    float* __restrict__ tvmn, float* __restrict__ tvmx) {
  __shared__ __align__(16) i8 As[2 * 128 * 64], Bs[2 * 128 * 64];
  int bx, by; xcd_swz(bx, by);
  const int which = bx >> 4;
  const int bn = (bx & 15) * 128;
  const int bm = by * 128;
  const i8* B = (which == 0) ? Bq : (which == 1) ? Bk : Bv;
  const float* sb = (which == 0) ? sbq : (which == 1) ? sbk : sbv;
  const float* zb = (which == 0) ? zbq : (which == 1) ? zbk : zbv;
  const float* Sb0 = (which == 0) ? Sq0 : (which == 1) ? Sk0 : Sv0;
  const float* Sb1 = (which == 0) ? Sq1 : (which == 1) ? Sk1 : Sv1;
  const float* bias = (which == 0) ? biasq : (which == 1) ? biask : biasv;
  u16* C = (which == 0) ? Cq : (which == 1) ? Ck : Cv;
  float* tmn = (which == 0) ? tqmn : (which == 1) ? tkmn : tvmn;
  float* tmx = (which == 0) ? tqmx : (which == 1) ? tkmx : tvmx;
  const float alpha = (which == 0) ? 0.125f : 1.0f;

  i32x4 acc[4][4] = {};
  gemm128_i8_db(A, B, D_DIM, bm, bn, 0, D_DIM, As, Bs, acc);

  const int tid = threadIdx.x;
  const int wid = tid >> 6, lane = tid & 63;
  const int wr = wid >> 1, wc = wid & 1;
  const int lr = lane & 15, lk = lane >> 4;
  const int col0 = bn + wc * 64 + lr;
  const int rbase = bm + wr * 64 + lk * 4;
  const int tci = (bn >> 6) + wc;     // NT = 32
  float sbc[4], zbc[4], Sbc[4], bc[4];
#pragma unroll
  for (int ni = 0; ni < 4; ++ni) {
    const int col = col0 + ni * 16;
    sbc[ni] = sb[col]; zbc[ni] = zb[col];
    Sbc[ni] = Sb0[col] + Sb1[col]; bc[ni] = bias[col];
  }
#pragma unroll
  for (int mi = 0; mi < 4; ++mi) {
#pragma unroll
    for (int r = 0; r < 4; ++r) {
      const int row = rbase + mi * 16 + r;
      const float sar = sx[row], zar = zx[row];
      const float Sar = Sx0[row] + Sx1[row];
      float v[4];
#pragma unroll
      for (int ni = 0; ni < 4; ++ni) {
        float ci = (float)acc[mi][ni][r] + zar * Sbc[ni] + zbc[ni] * Sar +
                   2048.0f * zar * zbc[ni];
        v[ni] = (sar * sbc[ni] * ci + bc[ni]) * alpha;
      }
#pragma unroll
      for (int ni = 0; ni < 4; ++ni)
        C[(size_t)row * D_DIM + col0 + ni * 16] = f32_to_bf16_rne(v[ni]);
      float mnv = fminf(fminf(v[0], v[1]), fminf(v[2], v[3]));
      float mxv = fmaxf(fmaxf(v[0], v[1]), fmaxf(v[2], v[3]));
      mnv = fminf(mnv, __shfl_xor(mnv, 1, 64)); mxv = fmaxf(mxv, __shfl_xor(mxv, 1, 64));
      mnv = fminf(mnv, __shfl_xor(mnv, 2, 64)); mxv = fmaxf(mxv, __shfl_xor(mxv, 2, 64));
      mnv = fminf(mnv, __shfl_xor(mnv, 4, 64)); mxv = fmaxf(mxv, __shfl_xor(mxv, 4, 64));
      mnv = fminf(mnv, __shfl_xor(mnv, 8, 64)); mxv = fmaxf(mxv, __shfl_xor(mxv, 8, 64));
      if (lr == 0) {
        tmn[(size_t)row * 32 + tci] = mnv;
        tmx[(size_t)row * 32 + tci] = mxv;
      }
    }
  }
}

// ---- W1 (i8): relu epilogue; 4 blocks/CU ----
__global__ __launch_bounds__(256, 4) void gemm_w1_i8(
    const i8* __restrict__ A, const float* __restrict__ sx, const float* __restrict__ zx,
    const float* __restrict__ Sx0, const float* __restrict__ Sx1,
    const i8* __restrict__ B, const float* __restrict__ sb, const float* __restrict__ zb,
    const float* __restrict__ Sb0, const float* __restrict__ Sb1,
    const float* __restrict__ bias, u16* __restrict__ C, float* __restrict__ tmx) {
  __shared__ __align__(16) i8 As[2 * 128 * 64], Bs[2 * 128 * 64];
  int bx, by; xcd_swz(bx, by);
  const int bn = bx * 128, bm = by * 128;

  i32x4 acc[4][4] = {};
  gemm128_i8_db(A, B, D_DIM, bm, bn, 0, D_DIM, As, Bs, acc);

  const int tid = threadIdx.x;
  const int wid = tid >> 6, lane = tid & 63;
  const int wr = wid >> 1, wc = wid & 1;
  const int lr = lane & 15, lk = lane >> 4;
  const int col0 = bn + wc * 64 + lr;
  const int rbase = bm + wr * 64 + lk * 4;
  const int tci = (bn >> 6) + wc;     // NT = 128
  float sbc[4], zbc[4], Sbc[4], bc[4];
#pragma unroll
  for (int ni = 0; ni < 4; ++ni) {
    const int col = col0 + ni * 16;
    sbc[ni] = sb[col]; zbc[ni] = zb[col];
    Sbc[ni] = Sb0[col] + Sb1[col]; bc[ni] = bias[col];
  }
#pragma unroll
  for (int mi = 0; mi < 4; ++mi) {
#pragma unroll
    for (int r = 0; r < 4; ++r) {
      const int row = rbase + mi * 16 + r;
      const float sar = sx[row], zar = zx[row];
      const float Sar = Sx0[row] + Sx1[row];
      float v[4];
#pragma unroll
      for (int ni = 0; ni < 4; ++ni) {
        float ci = (float)acc[mi][ni][r] + zar * Sbc[ni] + zbc[ni] * Sar +
                   2048.0f * zar * zbc[ni];
        v[ni] = fmaxf(sar * sbc[ni] * ci + bc[ni], 0.f);
      }
#pragma unroll
      for (int ni = 0; ni < 4; ++ni)
        C[(size_t)row * FF_DIM + col0 + ni * 16] = f32_to_bf16_rne(v[ni]);
      float mxv = fmaxf(fmaxf(v[0], v[1]), fmaxf(v[2], v[3]));
      mxv = fmaxf(mxv, __shfl_xor(mxv, 1, 64));
      mxv = fmaxf(mxv, __shfl_xor(mxv, 2, 64));
      mxv = fmaxf(mxv, __shfl_xor(mxv, 4, 64));
      mxv = fmaxf(mxv, __shfl_xor(mxv, 8, 64));
      if (lr == 0) tmx[(size_t)row * 128 + tci] = mxv;
    }
  }
}

// ---- split-K partial (i8): raw acc only ----
__global__ __launch_bounds__(256, 4) void gemm_splitk_i8(
    const i8* __restrict__ A, const i8* __restrict__ B,
    float* __restrict__ part, int K, int nsplit) {
  __shared__ __align__(16) i8 As[2 * 128 * 64], Bs[2 * 128 * 64];
  int bx, by; xcd_swz(bx, by);
  const int bm = by * 128, bn = bx * 128;
  const int ks = blockIdx.z;
  const int kchunk = K / nsplit;
  i32x4 acc[4][4] = {};
  gemm128_i8_db(A, B, K, bm, bn, ks * kchunk, (ks + 1) * kchunk, As, Bs, acc);

  float* dst = part + (size_t)ks * S_LEN * D_DIM;
  const int tid = threadIdx.x;
  const int wid = tid >> 6, lane = tid & 63;
  const int wr = wid >> 1, wc = wid & 1;
  const int lr = lane & 15, lk = lane >> 4;
  const int col0 = bn + wc * 64 + lr;
  const int rbase = bm + wr * 64 + lk * 4;
#pragma unroll
  for (int ni = 0; ni < 4; ++ni) {
    const int col = col0 + ni * 16;
#pragma unroll
    for (int mi = 0; mi < 4; ++mi)
#pragma unroll
      for (int r = 0; r < 4; ++r)
        dst[(size_t)(rbase + mi * 16 + r) * D_DIM + col] = (float)acc[mi][ni][r];
  }
}

// ---- reduce of 4 raw partials + full zero-point correction + bias (+res) ----
__global__ __launch_bounds__(256) void splitk_reduce4(
    const float* __restrict__ part,
    const float* __restrict__ sxa, const float* __restrict__ zxa,
    const float* __restrict__ Sxa0, const float* __restrict__ Sxa1,
    const float* __restrict__ sw, const float* __restrict__ zw,
    const float* __restrict__ Sw0, const float* __restrict__ Sw1,
    float Kf, const float* __restrict__ bias, const float* __restrict__ res,
    float* __restrict__ out) {
  const size_t st4 = (size_t)S_LEN * D_DIM / 4;
  for (size_t i = (size_t)blockIdx.x * 256 + threadIdx.x; i < st4;
       i += (size_t)gridDim.x * 256) {
    const int row = (int)(i >> 9);
    const int c4 = (int)(i & 511);
    float4 s = ((const float4*)part)[i];
    float4 p1 = ((const float4*)part)[i + st4];
    float4 p2 = ((const float4*)part)[i + 2 * st4];
    float4 p3 = ((const float4*)part)[i + 3 * st4];
    s.x += p1.x + p2.x + p3.x; s.y += p1.y + p2.y + p3.y;
    s.z += p1.z + p2.z + p3.z; s.w += p1.w + p2.w + p3.w;
    const float sxr = sxa[row], zxr = zxa[row];
    const float Sxr = Sxa0[row] + Sxa1[row];
    float4 ws = ((const float4*)sw)[c4];
    float4 wz = ((const float4*)zw)[c4];
    float4 w0 = ((const float4*)Sw0)[c4];
    float4 w1 = ((const float4*)Sw1)[c4];
    float4 b4 = ((const float4*)bias)[c4];
    float4 o;
    o.x = sxr * ws.x * (s.x + zxr * (w0.x + w1.x) + wz.x * Sxr + Kf * zxr * wz.x) + b4.x;
    o.y = sxr * ws.y * (s.y + zxr * (w0.y + w1.y) + wz.y * Sxr + Kf * zxr * wz.y) + b4.y;
    o.z = sxr * ws.z * (s.z + zxr * (w0.z + w1.z) + wz.z * Sxr + Kf * zxr * wz.z) + b4.z;
    o.w = sxr * ws.w * (s.w + zxr * (w0.w + w1.w) + wz.w * Sxr + Kf * zxr * wz.w) + b4.w;
    if (res) {
      float4 r = ((const float4*)res)[i];
      o.x += r.x; o.y += r.y; o.z += r.z; o.w += r.w;
    }
    ((float4*)out)[i] = o;
  }
}

// ---- fused: h2 = corrected(sum parts)+bias+res; LN; quant -> i8 + NEW params ----
__global__ __launch_bounds__(256) void splitk_reduce_ln(
    const float* __restrict__ part,
    const float* __restrict__ sxa, const float* __restrict__ zxa,
    const float* __restrict__ Sxa0, const float* __restrict__ Sxa1,
    const float* __restrict__ sw, const float* __restrict__ zw,
    const float* __restrict__ Sw0, const float* __restrict__ Sw1,
    const float* __restrict__ bias, const float* __restrict__ res,
    float* __restrict__ h2out,
    const float* __restrict__ g, const float* __restrict__ bvec,
    i8* __restrict__ out, float* __restrict__ srow, float* __restrict__ zrow,
    float* __restrict__ S0row, float* __restrict__ S1row) {
  __shared__ float red[8];
  const int row = blockIdx.x, tid = threadIdx.x;
  const size_t st = (size_t)S_LEN * D_DIM;
  const float4* p0 = (const float4*)(part + (size_t)row * D_DIM);
  const float4* p1 = (const float4*)(part + st + (size_t)row * D_DIM);
  const float4* p2 = (const float4*)(part + 2 * st + (size_t)row * D_DIM);
  const float4* p3 = (const float4*)(part + 3 * st + (size_t)row * D_DIM);
  const float4* rr = (const float4*)(res + (size_t)row * D_DIM);
  const float4* b4 = (const float4*)bias;
  const float4* g4 = (const float4*)g;
  const float4* e4 = (const float4*)bvec;

  const float sxr = sxa[row], zxr = zxa[row];
  const float Sxr = Sxa0[row] + Sxa1[row];

  float4 v0, v1;
#pragma unroll
  for (int h = 0; h < 2; ++h) {
    const int idx = tid + h * 256;
    float4 a = p0[idx], q = p1[idx], u = p2[idx], w = p3[idx];
    float4 ws = ((const float4*)sw)[idx];
    float4 wz = ((const float4*)zw)[idx];
    float4 s0 = ((const float4*)Sw0)[idx];
    float4 s1 = ((const float4*)Sw1)[idx];
    float4 bb = b4[idx], rv = rr[idx];
    float4 o;
    o.x = sxr * ws.x * (a.x + q.x + u.x + w.x + zxr * (s0.x + s1.x) + wz.x * Sxr + 2048.0f * zxr * wz.x) + bb.x + rv.x;
    o.y = sxr * ws.y * (a.y + q.y + u.y + w.y + zxr * (s0.y + s1.y) + wz.y * Sxr + 2048.0f * zxr * wz.y) + bb.y + rv.y;
    o.z = sxr * ws.z * (a.z + q.z + u.z + w.z + zxr * (s0.z + s1.z) + wz.z * Sxr + 2048.0f * zxr * wz.z) + bb.z + rv.z;
    o.w = sxr * ws.w * (a.w + q.w + u.w + w.w + zxr * (s0.w + s1.w) + wz.w * Sxr + 2048.0f * zxr * wz.w) + bb.w + rv.w;
    if (h == 0) v0 = o; else v1 = o;
  }
  float* h2r = h2out + (size_t)row * D_DIM;
  *(float4*)&h2r[tid * 4] = v0;
  *(float4*)&h2r[1024 + tid * 4] = v1;

  float s = v0.x + v0.y + v0.z + v0.w + v1.x + v1.y + v1.z + v1.w;
  float ss = v0.x * v0.x + v0.y * v0.y + v0.z * v0.z + v0.w * v0.w +
             v1.x * v1.x + v1.y * v1.y + v1.z * v1.z + v1.w * v1.w;
  s = wred_sum(s); ss = wred_sum(ss);
  if ((tid & 63) == 0) { red[tid >> 6] = s; red[4 + (tid >> 6)] = ss; }
  __syncthreads();
  float mu = (red[0] + red[1] + red[2] + red[3]) / (float)D_DIM;
  float var = (red[4] + red[5] + red[6] + red[7]) / (float)D_DIM - mu * mu;
  float rstd = 1.0f / sqrtf(var + 1e-5f);
  __syncthreads();

  float mn = 0.f, mx = 0.f;
  float4 n0, n1;
  {
    float4 gg = g4[tid], bb = e4[tid];
    n0.x = (v0.x - mu) * rstd * gg.x + bb.x; n0.y = (v0.y - mu) * rstd * gg.y + bb.y;
    n0.z = (v0.z - mu) * rstd * gg.z + bb.z; n0.w = (v0.w - mu) * rstd * gg.w + bb.w;
    gg = g4[tid + 256]; bb = e4[tid + 256];
    n1.x = (v1.x - mu) * rstd * gg.x + bb.x; n1.y = (v1.y - mu) * rstd * gg.y + bb.y;
    n1.z = (v1.z - mu) * rstd * gg.z + bb.z; n1.w = (v1.w - mu) * rstd * gg.w + bb.w;
    mn = fminf(mn, fminf(fminf(n0.x, n0.y), fminf(n0.z, n0.w)));
    mn = fminf(mn, fminf(fminf(n1.x, n1.y), fminf(n1.z, n1.w)));
    mx = fmaxf(mx, fmaxf(fmaxf(n0.x, n0.y), fmaxf(n0.z, n0.w)));
    mx = fmaxf(mx, fmaxf(fmaxf(n1.x, n1.y), fmaxf(n1.z, n1.w)));
  }
  mn = wred_min(mn); mx = wred_max(mx);
  if ((tid & 63) == 0) { red[tid >> 6] = mn; red[4 + (tid >> 6)] = mx; }
  __syncthreads();
  mn = fminf(fminf(red[0], red[1]), fminf(red[2], red[3]));
  mx = fmaxf(fmaxf(red[4], red[5]), fmaxf(red[6], red[7]));
  float scale = fmaxf((mx - mn) / QMAX, 1e-5f);
  float zp = rintf(-mn / scale);
  if (tid == 0) { srow[row] = scale; zrow[row] = 128.0f - zp; }
  float q00 = fminf(fmaxf(rintf(n0.x / scale) + zp, 0.f), QMAX);
  float q01 = fminf(fmaxf(rintf(n0.y / scale) + zp, 0.f), QMAX);
  float q02 = fminf(fmaxf(rintf(n0.z / scale) + zp, 0.f), QMAX);
  float q03 = fminf(fmaxf(rintf(n0.w / scale) + zp, 0.f), QMAX);
  float q10 = fminf(fmaxf(rintf(n1.x / scale) + zp, 0.f), QMAX);
  float q11 = fminf(fmaxf(rintf(n1.y / scale) + zp, 0.f), QMAX);
  float q12 = fminf(fmaxf(rintf(n1.z / scale) + zp, 0.f), QMAX);
  float q13 = fminf(fmaxf(rintf(n1.w / scale) + zp, 0.f), QMAX);
  *(int*)&out[(size_t)row * D_DIM + tid * 4] = pack4_i8(q00, q01, q02, q03);
  *(int*)&out[(size_t)row * D_DIM + 1024 + tid * 4] = pack4_i8(q10, q11, q12, q13);
  float s0 = q00 + q01 + q02 + q03 - 512.f;
  float s1 = q10 + q11 + q12 + q13 - 512.f;
  __syncthreads();
  s0 = wred_sum(s0); s1 = wred_sum(s1);
  if ((tid & 63) == 0) { red[tid >> 6] = s0; red[4 + (tid >> 6)] = s1; }
  __syncthreads();
  if (tid == 0) {
    S0row[row] = red[0] + red[1] + red[2] + red[3];
    S1row[row] = red[4] + red[5] + red[6] + red[7];
  }
}

// ---- attention pass A: per-row max (t-units) + denom. LDS = Ks only (9 KB). ----
__global__ __launch_bounds__(256) void attn_ml(
    const u16* __restrict__ qi, const float* __restrict__ sq,
    const u16* __restrict__ ki, const float* __restrict__ sk,
    float* __restrict__ Mb, float* __restrict__ Lb) {
  __shared__ __align__(16) u16 Ks[64][72];
  int h, ti; attn_map(blockIdx.x, h, ti);
  const int i0 = ti * 64;
  const int tid = threadIdx.x;
  const int wid = tid >> 6, lane = tid & 63;
  const int lr = lane & 15, g = lane >> 4;
  const size_t hbase = (size_t)h * HD_DIM;

  const int r_a = tid >> 3, ch_a = tid & 7;
  const int r_b = 32 + r_a;

  const bf16x8 aq0 = *(const bf16x8*)&qi[(size_t)(i0 + wid * 16 + lr) * D_DIM + hbase + g * 8];
  const bf16x8 aq1 = *(const bf16x8*)&qi[(size_t)(i0 + wid * 16 + lr) * D_DIM + hbase + 32 + g * 8];
  float sq2[4];
#pragma unroll
  for (int r = 0; r < 4; ++r) sq2[r] = sq[i0 + wid * 16 + g * 4 + r] * LOG2E;

  const int ntiles = i0 / 64 + 1;
  float m_r[4] = {-1e30f, -1e30f, -1e30f, -1e30f};
  float l_r[4] = {0.f, 0.f, 0.f, 0.f};

  float4 ka0 = *(const float4*)&ki[(size_t)r_a * D_DIM + hbase + ch_a * 8];
  float4 ka1 = *(const float4*)&ki[(size_t)r_b * D_DIM + hbase + ch_a * 8];
  for (int t = 0; t < ntiles; ++t) {
    __syncthreads();
    *(float4*)&Ks[r_a][ch_a * 8] = ka0;
    *(float4*)&Ks[r_b][ch_a * 8] = ka1;
    __syncthreads();
    if (t + 1 < ntiles) {
      const int jn = (t + 1) * 64;
      ka0 = *(const float4*)&ki[(size_t)(jn + r_a) * D_DIM + hbase + ch_a * 8];
      ka1 = *(const float4*)&ki[(size_t)(jn + r_b) * D_DIM + hbase + ch_a * 8];
    }

    f32x4 accs[4] = {};
#pragma unroll
    for (int ni = 0; ni < 4; ++ni) {
      bf16x8 b0 = *(const bf16x8*)&Ks[ni * 16 + lr][g * 8];
      bf16x8 b1 = *(const bf16x8*)&Ks[ni * 16 + lr][32 + g * 8];
      accs[ni] = __builtin_amdgcn_mfma_f32_16x16x32_bf16(aq0, b0, accs[ni], 0, 0, 0);
      accs[ni] = __builtin_amdgcn_mfma_f32_16x16x32_bf16(aq1, b1, accs[ni], 0, 0, 0);
    }

    const int jt = t * 64;
    float tv[4][4];
#pragma unroll
    for (int ni = 0; ni < 4; ++ni) {
      const float skc = sk[jt + ni * 16 + lr];
#pragma unroll
      for (int r = 0; r < 4; ++r) tv[ni][r] = accs[ni][r] * sq2[r] * skc;
    }
    if (t == ntiles - 1) {
      const int jcol = jt + lr, irow = i0 + wid * 16 + g * 4;
#pragma unroll
      for (int ni = 0; ni < 4; ++ni)
#pragma unroll
        for (int r = 0; r < 4; ++r)
          if (jcol + ni * 16 > irow + r) tv[ni][r] = -1e30f;
    }
#pragma unroll
    for (int r = 0; r < 4; ++r) {
      float tmax = fmaxf(fmaxf(tv[0][r], tv[1][r]), fmaxf(tv[2][r], tv[3][r]));
      tmax = fmaxf(tmax, __shfl_xor(tmax, 1, 64));
      tmax = fmaxf(tmax, __shfl_xor(tmax, 2, 64));
      tmax = fmaxf(tmax, __shfl_xor(tmax, 4, 64));
      tmax = fmaxf(tmax, __shfl_xor(tmax, 8, 64));
      float mnew = fmaxf(m_r[r], tmax);
      float sum = exp2f(tv[0][r] - mnew) + exp2f(tv[1][r] - mnew) +
                  exp2f(tv[2][r] - mnew) + exp2f(tv[3][r] - mnew);
      sum += __shfl_xor(sum, 1, 64);
      sum += __shfl_xor(sum, 2, 64);
      sum += __shfl_xor(sum, 4, 64);
      sum += __shfl_xor(sum, 8, 64);
      l_r[r] = l_r[r] * exp2f(m_r[r] - mnew) + sum;
      m_r[r] = mnew;
    }
  }

  if (lr == 0) {
#pragma unroll
    for (int r = 0; r < 4; ++r) {
      const int row = i0 + wid * 16 + g * 4 + r;
      Mb[(size_t)h * S_LEN + row] = m_r[r];   // t-units (log2 domain)
      Lb[(size_t)h * S_LEN + row] = l_r[r];
    }
  }
}

// ---- attention pass B: quantized probs @ V. LDS = Ks+Ps+Vt (27 KB). ----
__global__ __launch_bounds__(256) void attn_pv(
    const u16* __restrict__ qi, const float* __restrict__ sq,
    const u16* __restrict__ ki, const float* __restrict__ sk,
    const u16* __restrict__ vt,   // per-head V^T: [H][64][S]
    const float* __restrict__ Mb, const float* __restrict__ Lb,
    float* __restrict__ ctx) {
  __shared__ __align__(16) u16 Ks[64][72];
  __shared__ __align__(16) u16 Ps[64][72];
  __shared__ __align__(16) u16 Vt[64][72];
  int h, ti; attn_map(blockIdx.x, h, ti);
  const int i0 = ti * 64;
  const int tid = threadIdx.x;
  const int wid = tid >> 6, lane = tid & 63;
  const int lr = lane & 15, g = lane >> 4;
  const size_t hbase = (size_t)h * HD_DIM;
  const size_t vtbase = (size_t)h * HD_DIM * S_LEN;

  const int r_a = tid >> 3, ch_a = tid & 7;
  const int r_b = 32 + r_a;

  const bf16x8 aq0 = *(const bf16x8*)&qi[(size_t)(i0 + wid * 16 + lr) * D_DIM + hbase + g * 8];
  const bf16x8 aq1 = *(const bf16x8*)&qi[(size_t)(i0 + wid * 16 + lr) * D_DIM + hbase + 32 + g * 8];

  float sq2[4], b_r[4], qsc[4];
#pragma unroll
  for (int r = 0; r < 4; ++r) {
    const int row = i0 + wid * 16 + g * 4 + r;
    sq2[r] = sq[row] * LOG2E;
    float m_t = Mb[(size_t)h * S_LEN + row];
    float li = Lb[(size_t)h * S_LEN + row];
    float sc = fmaxf((1.0f / li) / QMAX, 1e-5f);
    qsc[r] = sc;
    b_r[r] = m_t - log2f(1.0f / (li * sc));   // q8 = rint(exp2(t - b_r))
  }

  const int ntiles = i0 / 64 + 1;
  f32x4 acco[4] = {};
  float4 kb0 = *(const float4*)&ki[(size_t)r_a * D_DIM + hbase + ch_a * 8];
  float4 kb1 = *(const float4*)&ki[(size_t)r_b * D_DIM + hbase + ch_a * 8];
  float4 vb0 = *(const float4*)&vt[vtbase + (size_t)r_a * S_LEN + ch_a * 8];
  float4 vb1 = *(const float4*)&vt[vtbase + (size_t)r_b * S_LEN + ch_a * 8];
  for (int t = 0; t < ntiles; ++t) {
    __syncthreads();
    *(float4*)&Ks[r_a][ch_a * 8] = kb0;
    *(float4*)&Ks[r_b][ch_a * 8] = kb1;
    *(float4*)&Vt[r_a][ch_a * 8] = vb0;
    *(float4*)&Vt[r_b][ch_a * 8] = vb1;
    __syncthreads();
    if (t + 1 < ntiles) {
      const int jn = (t + 1) * 64;
      kb0 = *(const float4*)&ki[(size_t)(jn + r_a) * D_DIM + hbase + ch_a * 8];
      kb1 = *(const float4*)&ki[(size_t)(jn + r_b) * D_DIM + hbase + ch_a * 8];
      vb0 = *(const float4*)&vt[vtbase + (size_t)r_a * S_LEN + jn + ch_a * 8];
      vb1 = *(const float4*)&vt[vtbase + (size_t)r_b * S_LEN + jn + ch_a * 8];
    }

    f32x4 accs[4] = {};
#pragma unroll
    for (int ni = 0; ni < 4; ++ni) {
      bf16x8 b0 = *(const bf16x8*)&Ks[ni * 16 + lr][g * 8];
      bf16x8 b1 = *(const bf16x8*)&Ks[ni * 16 + lr][32 + g * 8];
      accs[ni] = __builtin_amdgcn_mfma_f32_16x16x32_bf16(aq0, b0, accs[ni], 0, 0, 0);
      accs[ni] = __builtin_amdgcn_mfma_f32_16x16x32_bf16(aq1, b1, accs[ni], 0, 0, 0);
    }

    const int jt = t * 64;
    const bool diag = (t == ntiles - 1);
    const int jcol = jt + lr, irow = i0 + wid * 16 + g * 4;
#pragma unroll
    for (int ni = 0; ni < 4; ++ni) {
      const float skc = sk[jt + ni * 16 + lr];
#pragma unroll
      for (int r = 0; r < 4; ++r) {
        float tvv = accs[ni][r] * sq2[r] * skc;
        if (diag && (jcol + ni * 16 > irow + r)) tvv = -1e30f;
        float q8 = fminf(rintf(exp2f(tvv - b_r[r])), QMAX);   // exp2>=0
        Ps[wid * 16 + g * 4 + r][ni * 16 + lr] = f32i_to_bf16(q8);
      }
    }
    // Ps rows for this wave are wave-local: no barrier needed

    bf16x8 ap0 = *(const bf16x8*)&Ps[wid * 16 + lr][g * 8];
    bf16x8 ap1 = *(const bf16x8*)&Ps[wid * 16 + lr][32 + g * 8];
#pragma unroll
    for (int ni = 0; ni < 4; ++ni) {
      bf16x8 b0 = *(const bf16x8*)&Vt[ni * 16 + lr][g * 8];
      bf16x8 b1 = *(const bf16x8*)&Vt[ni * 16 + lr][32 + g * 8];
      acco[ni] = __builtin_amdgcn_mfma_f32_16x16x32_bf16(ap0, b0, acco[ni], 0, 0, 0);
      acco[ni] = __builtin_amdgcn_mfma_f32_16x16x32_bf16(ap1, b1, acco[ni], 0, 0, 0);
    }
  }

#pragma unroll
  for (int ni = 0; ni < 4; ++ni)
#pragma unroll
    for (int r = 0; r < 4; ++r) {
      const int row = i0 + wid * 16 + g * 4 + r;
      ctx[(size_t)row * D_DIM + hbase + ni * 16 + lr] = acco[ni][r] * qsc[r];
    }
}

extern "C" void kernel_launch(void* const* d_in, const int* in_sizes, int n_in,
                              void* d_out, int out_size, void* d_ws, size_t ws_size,
                              hipStream_t stream) {
  (void)in_sizes; (void)n_in; (void)out_size;
  const float* hs  = (const float*)d_in[0];
  const float* Wq  = (const float*)d_in[2];
  const float* bq  = (const float*)d_in[3];
  const float* Wk  = (const float*)d_in[4];
  const float* bk  = (const float*)d_in[5];
  const float* Wv  = (const float*)d_in[6];
  const float* bv  = (const float*)d_in[7];
  const float* Wo  = (const float*)d_in[8];
  const float* bo  = (const float*)d_in[9];
  const float* g1  = (const float*)d_in[10];
  const float* be1 = (const float*)d_in[11];
  const float* W1  = (const float*)d_in[12];
  const float* bf1 = (const float*)d_in[13];
  const float* W2  = (const float*)d_in[14];
  const float* bf2 = (const float*)d_in[15];
  const float* g2  = (const float*)d_in[16];
  const float* be2 = (const float*)d_in[17];
  float* out = (float*)d_out;

  const size_t SD = (size_t)S_LEN * D_DIM;
  const size_t SF = (size_t)S_LEN * FF_DIM;
  const size_t HS = (size_t)H_NUM * S_LEN;

  char* p = (char*)d_ws;
  auto alloc = [&](size_t bytes) { char* r = p; p += (bytes + 255) & ~(size_t)255; return r; };

  float* h2   = (float*)alloc(SD * 4);
  float* sx   = (float*)alloc(S_LEN * 4);
  float* zx   = (float*)alloc(S_LEN * 4);
  float* Sx0  = (float*)alloc(S_LEN * 4);
  float* Sx1  = (float*)alloc(S_LEN * 4);
  float* sy   = (float*)alloc(S_LEN * 4);
  float* zy   = (float*)alloc(S_LEN * 4);
  float* Sy0  = (float*)alloc(S_LEN * 4);
  float* Sy1  = (float*)alloc(S_LEN * 4);
  float* sxf  = (float*)alloc(S_LEN * 4);
  float* zxf  = (float*)alloc(S_LEN * 4);
  float* Sf0  = (float*)alloc(S_LEN * 4);
  float* Sf1  = (float*)alloc(S_LEN * 4);
  float* sqv  = (float*)alloc(S_LEN * 4);
  float* skv  = (float*)alloc(S_LEN * 4);
  float* Mb   = (float*)alloc(HS * 4);
  float* Lbv  = (float*)alloc(HS * 4);
  float* swq = (float*)alloc(D_DIM * 4); float* zwq = (float*)alloc(D_DIM * 4);
  float* Sq0 = (float*)alloc(D_DIM * 4); float* Sq1 = (float*)alloc(D_DIM * 4);
  float* swk = (float*)alloc(D_DIM * 4); float* zwk = (float*)alloc(D_DIM * 4);
  float* Sk0 = (float*)alloc(D_DIM * 4); float* Sk1 = (float*)alloc(D_DIM * 4);
  float* swv = (float*)alloc(D_DIM * 4); float* zwv = (float*)alloc(D_DIM * 4);
  float* Sv0 = (float*)alloc(D_DIM * 4); float* Sv1 = (float*)alloc(D_DIM * 4);
  float* swo = (float*)alloc(D_DIM * 4); float* zwo = (float*)alloc(D_DIM * 4);
  float* So0 = (float*)alloc(D_DIM * 4); float* So1 = (float*)alloc(D_DIM * 4);
  float* sw1 = (float*)alloc(FF_DIM * 4); float* zw1 = (float*)alloc(FF_DIM * 4);
  float* S10 = (float*)alloc(FF_DIM * 4); float* S11 = (float*)alloc(FF_DIM * 4);
  float* sw2 = (float*)alloc(D_DIM * 4); float* zw2 = (float*)alloc(D_DIM * 4);
  float* S20 = (float*)alloc(D_DIM * 4); float* S21 = (float*)alloc(D_DIM * 4);
  float* tqmn = (float*)alloc(S_LEN * 32 * 4);
  float* tqmx = (float*)alloc(S_LEN * 32 * 4);
  float* tkmn = (float*)alloc(S_LEN * 32 * 4);
  float* tkmx = (float*)alloc(S_LEN * 32 * 4);
  float* tvmn = (float*)alloc(S_LEN * 32 * 4);
  float* tvmx = (float*)alloc(S_LEN * 32 * 4);
  float* tf1x = (float*)alloc(S_LEN * 128 * 4);
  i8* xi  = (i8*)alloc(SD);
  i8* wqi = (i8*)alloc(SD);
  i8* wki = (i8*)alloc(SD);
  i8* wvi = (i8*)alloc(SD);
  i8* woi = (i8*)alloc(SD);
  i8* w1i = (i8*)alloc(SF);
  i8* w2i = (i8*)alloc(SF);
  i8* f1i = (i8*)alloc(SF);
  char* arena = alloc(8 * SD * 2);   // 64 MB, phase-aliased
  // phase QKV/attn:
  u16* qv   = (u16*)arena;                  // unit 0 (dead after requant3)
  u16* kv   = qv + SD;
  u16* vv   = kv + SD;
  u16* qi8  = vv + SD;
  u16* ki8  = qi8 + SD;
  u16* vfb  = ki8 + SD;
  float* ctxb = (float*)(vfb + SD);         // units 6-8
  u16* vtb  = qv;                           // V^T, aliases dead qv (unit 0)
  // phase Wo / W2: 4 x SD fp32 raw partials = whole arena
  float* pwo = (float*)arena;
  // phase FFN:
  u16* f1v = (u16*)arena;
  float* pw2 = (float*)arena;
  size_t need = (size_t)(p - (char*)d_ws);
  if (ws_size < need) return;

  dim3 blk(256);

  wquantD_i8<<<4 * D_DIM + FF_DIM, blk, 0, stream>>>(
      Wq, wqi, swq, zwq, Sq0, Sq1,
      Wk, wki, swk, zwk, Sk0, Sk1,
      Wv, wvi, swv, zwv, Sv0, Sv1,
      Wo, woi, swo, zwo, So0, So1,
      W1, w1i, sw1, zw1, S10, S11);
  wquantW2_i8<<<D_DIM, blk, 0, stream>>>(W2, w2i, sw2, zw2, S20, S21);

  ln_quant_i8<<<S_LEN, blk, 0, stream>>>(hs, g1, be1, xi, sx, zx, Sx0, Sx1);

  dim3 gqkv(3 * D_DIM / 128, S_LEN / 128);
  gemm_qkv_i8<<<gqkv, blk, 0, stream>>>(xi, sx, zx, Sx0, Sx1,
                                        wqi, swq, zwq, Sq0, Sq1, bq, qv, tqmn, tqmx,
                                        wki, swk, zwk, Sk0, Sk1, bk, kv, tkmn, tkmx,
                                        wvi, swv, zwv, Sv0, Sv1, bv, vv, tvmn, tvmx);

  requant3<<<3 * S_LEN, blk, 0, stream>>>(qv, tqmn, tqmx, qi8, sqv,
                                          kv, tkmn, tkmx, ki8, skv,
                                          vv, tvmn, tvmx, vfb);

  dim3 gtv(S_LEN / 64, H_NUM);
  transpose_v<<<gtv, blk, 0, stream>>>(vfb, vtb);

  const int ga = (S_LEN / 64) * H_NUM;   // 1024 blocks
  attn_ml<<<ga, blk, 0, stream>>>(qi8, sqv, ki8, skv, Mb, Lbv);
  attn_pv<<<ga, blk, 0, stream>>>(qi8, sqv, ki8, skv, vtb, Mb, Lbv, ctxb);

  act_quant_i8<<<S_LEN, blk, 0, stream>>>(ctxb, xi, sx, zx, Sx0, Sx1);

  // Wo: split-K=4, raw partials; fused reduce + residual + LN2 + quant
  dim3 gwo(D_DIM / 128, S_LEN / 128, 4);
  gemm_splitk_i8<<<gwo, blk, 0, stream>>>(xi, woi, pwo, D_DIM, 4);
  splitk_reduce_ln<<<S_LEN, blk, 0, stream>>>(pwo, sx, zx, Sx0, Sx1,
                                              swo, zwo, So0, So1, bo, hs, h2,
                                              g2, be2, xi, sy, zy, Sy0, Sy1);

  dim3 gff(FF_DIM / 128, S_LEN / 128);
  gemm_w1_i8<<<gff, blk, 0, stream>>>(xi, sy, zy, Sy0, Sy1,
                                      w1i, sw1, zw1, S10, S11, bf1, f1v, tf1x);
  requant_ff_i8<<<S_LEN, blk, 0, stream>>>(f1v, tf1x, f1i, sxf, zxf, Sf0, Sf1);

  // W2: split-K=4, raw partials
  dim3 gw2(D_DIM / 128, S_LEN / 128, 4);
  gemm_splitk_i8<<<gw2, blk, 0, stream>>>(f1i, w2i, pw2, FF_DIM, 4);
  splitk_reduce4<<<2048, blk, 0, stream>>>(pw2, sxf, zxf, Sf0, Sf1,
                                           sw2, zw2, S20, S21, (float)FF_DIM,
                                           bf2, h2, out);
}